// Round 14
// baseline (122.923 us; speedup 1.0000x reference)
//
#include <hip/hip_runtime.h>
#include <math.h>

#define NPIX 4096
#define KN 20
#define MTOT 327680.0    // B*N*K

__device__ inline unsigned long long shflx64(unsigned long long v, int m) {
  unsigned lo = (unsigned)v, hi = (unsigned)(v >> 32);
  lo = __shfl_xor(lo, m, 64);
  hi = __shfl_xor(hi, m, 64);
  return (((unsigned long long)hi) << 32) | lo;
}

// ===== K1: conv1 (5x5,1->64,tanh, zero-outside) + conv2 (3x3,64->32,tanh) =====
// Channel-major LDS (conflict-free lane-consecutive reads). conv2: cin split
// across 8 waves (8 cin each), ALL 32 couts per thread -> reuse=32 fmaf/LDS read.
// Cross-wave reduction via pad-9 LDS buffer, deterministic wave order.
__global__ __launch_bounds__(512) void conv12_k(const float* __restrict__ x,
    const float* __restrict__ c1w, const float* __restrict__ c1b,
    const float* __restrict__ c2w, const float* __restrict__ c2b,
    float* __restrict__ c2buf) {
  __shared__ float sx[224];          // 14x14 halo, stride 16
  __shared__ float sc1[7680];        // 64 ch x (10x10 halo, stride-12 rows)
  __shared__ float red[4608];        // 8 waves x 64 px x 9 (8 couts + pad)
  const int tid = threadIdx.x;
  const int l = tid & 63;
  const int w = __builtin_amdgcn_readfirstlane(tid >> 6);   // 8 waves, uniform
  const int b = blockIdx.x, tile = blockIdx.y;
  const int th = (tile >> 3) << 3, tw = (tile & 7) << 3;

  for (int i = tid; i < 196; i += 512) {
    int r = i / 14, c = i - r*14;
    int gr = th - 3 + r, gc = tw - 3 + c;
    sx[r*16 + c] = (gr>=0 && gr<64 && gc>=0 && gc<64) ? x[b*NPIX + (gr<<6) + gc] : 0.f;
  }
  __syncthreads();
  // conv1 on 10x10 halo; wave w -> couts w*8..+7; channel-major store
  for (int half = 0; half < 2; half++) {
    int px = l + (half << 6);
    if (px < 100) {
      int i = px / 10, j = px - i*10;
      int gy = th - 1 + i, gx = tw - 1 + j;
      bool inb = (gy>=0 && gy<64 && gx>=0 && gx<64);
      for (int cc = 0; cc < 8; cc++) {
        int co = (w << 3) + cc;
        float acc = c1b[co];
#pragma unroll
        for (int di=0; di<5; di++)
#pragma unroll
          for (int dj=0; dj<5; dj++)
            acc = fmaf(sx[(i+di)*16 + j+dj], c1w[co*25 + di*5 + dj], acc);
        sc1[co*120 + i*12 + j] = inb ? tanhf(acc) : 0.f;
      }
    }
  }
  __syncthreads();
  // conv2: thread = pixel (l), wave = cin-block (8 cin); all 32 couts in regs
  float acc[32];
  {
    int py = l >> 3, px2 = l & 7;
#pragma unroll
    for (int o=0;o<32;o++) acc[o] = (w == 0) ? c2b[o] : 0.f;
    for (int ci = 0; ci < 8; ci++) {
      int cin = (w << 3) + ci;
      const float* sp = sc1 + cin*120;
      float v[9];
#pragma unroll
      for (int di=0;di<3;di++)
#pragma unroll
        for (int dj=0;dj<3;dj++)
          v[di*3+dj] = sp[(py+di)*12 + px2+dj];
      const float* wc = c2w + cin*9;      // + co*576 per cout
#pragma unroll
      for (int o=0;o<32;o++) {
        const float* wo = wc + o*576;
#pragma unroll
        for (int t=0;t<9;t++)
          acc[o] = fmaf(v[t], wo[t], acc[o]);
      }
    }
  }
  // cross-wave reduction in 4 chunks of 8 couts
  {
    int py = l >> 3, px2 = l & 7;
    for (int ch = 0; ch < 4; ch++) {
      __syncthreads();
#pragma unroll
      for (int cc = 0; cc < 8; cc++)
        red[w*576 + l*9 + cc] = acc[(ch<<3) + cc];
      __syncthreads();
      // 512 threads: px = tid&63, coq = wave index
      float s = red[0*576 + l*9 + w];     // here w doubles as coq (0..7)
#pragma unroll
      for (int ww=1; ww<8; ww++) s += red[ww*576 + l*9 + w];
      int co = (ch<<3) + w;
      c2buf[(((size_t)b*32 + co) << 12) + ((th+py)<<6) + (tw+px2)] = tanhf(s);
    }
  }
}

// ===== K2: conv3 (3x3,32->16,tanh, zero-outside) + conv4 (3x3,16->1) =====
// conv3: cin split across 4 wave-pairs (8 cin each), all 16 couts per thread,
// computed on the 10x10 halo (128-thread px mapping, mask px<100).
__global__ __launch_bounds__(512) void conv34_k(const float* __restrict__ c2buf,
    const float* __restrict__ c3w, const float* __restrict__ c3b,
    const float* __restrict__ c4w, const float* __restrict__ c4b,
    float* __restrict__ fbuf) {
  __shared__ float sc2[4608];        // 32 ch x (12x12, stride-12 rows)
  __shared__ float sc3[1920];        // 16 ch x (10x10 halo, stride-12 rows)
  __shared__ float red[2000];        // 4 grp x 100 px x 5 (4 couts + pad)
  const int tid = threadIdx.x;
  const int b = blockIdx.x, tile = blockIdx.y;
  const int th = (tile >> 3) << 3, tw = (tile & 7) << 3;
  const int px = tid & 127;
  const int cinw = __builtin_amdgcn_readfirstlane(tid >> 7);  // 0..3, uniform

  for (int i = tid; i < 4608; i += 512) {
    int cin = i / 144, rem = i - cin*144;
    int rr = rem / 12, cc = rem - rr*12;
    int gr = th - 2 + rr, gc = tw - 2 + cc;
    float v = (gr>=0 && gr<64 && gc>=0 && gc<64)
              ? c2buf[(((size_t)b*32 + cin) << 12) + (gr<<6) + gc] : 0.f;
    sc2[cin*144 + rr*12 + cc] = v;
  }
  __syncthreads();
  float acc[16];
  int pi = px / 10, pj = px - pi*10;
  if (px < 100) {
#pragma unroll
    for (int o=0;o<16;o++) acc[o] = (cinw == 0) ? c3b[o] : 0.f;
    for (int ci = 0; ci < 8; ci++) {
      int cin = (cinw << 3) + ci;
      const float* sp = sc2 + cin*144;
      float v[9];
#pragma unroll
      for (int di=0;di<3;di++)
#pragma unroll
        for (int dj=0;dj<3;dj++)
          v[di*3+dj] = sp[(pi+di)*12 + pj+dj];
      const float* wc = c3w + cin*9;      // + co*288 per cout
#pragma unroll
      for (int o=0;o<16;o++) {
        const float* wo = wc + o*288;
#pragma unroll
        for (int t=0;t<9;t++)
          acc[o] = fmaf(v[t], wo[t], acc[o]);
      }
    }
  }
  // reduction in 4 chunks of 4 couts; then tanh -> sc3 (channel-major)
  int gy = th - 1 + pi, gx = tw - 1 + pj;
  bool inb = (gy>=0 && gy<64 && gx>=0 && gx<64);
  for (int ch = 0; ch < 4; ch++) {
    __syncthreads();
    if (px < 100) {
#pragma unroll
      for (int cc = 0; cc < 4; cc++)
        red[cinw*500 + px*5 + cc] = acc[(ch<<2) + cc];
    }
    __syncthreads();
    // 512 threads: px = tid&127 (<100), coq = tid>>7 (0..3)
    if (px < 100) {
      float s = red[0*500 + px*5 + cinw];  // cinw doubles as coq
#pragma unroll
      for (int g=1; g<4; g++) s += red[g*500 + px*5 + cinw];
      int co = (ch<<2) + cinw;
      sc3[co*120 + pi*12 + pj] = inb ? tanhf(s) : 0.f;
    }
  }
  __syncthreads();
  if (tid < 64) {
    int py = tid >> 3, qx = tid & 7;
    float acc4 = c4b[0];
    for (int cin = 0; cin < 16; cin++) {
#pragma unroll
      for (int di=0;di<3;di++)
#pragma unroll
        for (int dj=0;dj<3;dj++)
          acc4 = fmaf(sc3[cin*120 + (py+di)*12 + qx+dj], c4w[cin*9 + di*3+dj], acc4);
    }
    fbuf[b*NPIX + ((th+py)<<6) + (tw+qx)] = acc4;
  }
}

// ===== K3: per-batch sort: wave bitonic (256-runs) + merge-path =====
__global__ __launch_bounds__(1024) void sort2_k(const float* __restrict__ f,
    float* __restrict__ sval, int* __restrict__ sidx) {
  int b = blockIdx.x;
  int tid = threadIdx.x;
  int l = tid & 63, w = tid >> 6;
  __shared__ unsigned long long Ab[NPIX];
  __shared__ unsigned long long Bb[NPIX];
  const float* fb = f + b*NPIX;
  unsigned long long key[4];
#pragma unroll
  for (int r=0;r<4;r++) {
    unsigned e = (w<<8) + (r<<6) + l;
    float v = fb[e];
    unsigned u = __float_as_uint(v);
    u ^= (u >> 31) ? 0xFFFFFFFFu : 0x80000000u;   // order-preserving flip
    key[r] = (((unsigned long long)u) << 32) | e;
  }
  for (unsigned k = 2; k <= 256; k <<= 1) {
    for (unsigned j = k >> 1; j > 0; j >>= 1) {
      if (j >= 64) {
        unsigned rj = j >> 6;
#pragma unroll
        for (int r=0;r<4;r++) {
          int pr = r ^ (int)rj;
          if (pr > r) {
            unsigned e = (w<<8)+((unsigned)r<<6)+l;
            bool up = ((e & k & 255u) == 0);
            unsigned long long a = key[r], c = key[pr];
            bool sw = up ? (c < a) : (c > a);
            if (sw) { key[r] = c; key[pr] = a; }
          }
        }
      } else {
#pragma unroll
        for (int r=0;r<4;r++) {
          unsigned e = (w<<8)+((unsigned)r<<6)+l;
          unsigned long long a = key[r];
          unsigned long long p = shflx64(a, (int)j);
          bool up = ((e & k & 255u) == 0);
          bool keepmin = ((e & j) == 0) == up;
          key[r] = (keepmin ? (p < a) : (p > a)) ? p : a;
        }
      }
    }
  }
#pragma unroll
  for (int r=0;r<4;r++) Ab[(w<<8)+(r<<6)+l] = key[r];
  __syncthreads();
  unsigned long long* src = Ab;
  unsigned long long* dst = Bb;
  for (int lg = 8; lg <= 11; lg++) {
    const int L = 1 << lg;
    int p0 = tid << 2;
    int ri = p0 >> lg;
    int base = (ri ^ 1) << lg;
    int mbase = ((ri >> 1) << (lg + 1)) + (p0 & (L - 1));
    unsigned long long kk[4];
    int lo[4], hi[4];
#pragma unroll
    for (int r=0;r<4;r++) { kk[r] = src[p0 + r]; lo[r] = 0; hi[r] = L; }
    for (int s = 0; s <= lg; s++) {
#pragma unroll
      for (int r=0;r<4;r++) {
        if (lo[r] < hi[r]) {
          int mid = (lo[r] + hi[r]) >> 1;
          if (src[base + mid] < kk[r]) lo[r] = mid + 1; else hi[r] = mid;
        }
      }
    }
#pragma unroll
    for (int r=0;r<4;r++) dst[mbase + r + lo[r]] = kk[r];
    __syncthreads();
    unsigned long long* t = src; src = dst; dst = t;
  }
#pragma unroll
  for (int r=0;r<4;r++) {
    int p = (tid << 2) + r;
    unsigned long long kk = src[p];
    unsigned u = (unsigned)(kk >> 32);
    u ^= (u >> 31) ? 0x80000000u : 0xFFFFFFFFu;   // un-flip
    sval[b*NPIX + p] = __uint_as_float(u);
    sidx[b*NPIX + p] = (int)(kk & 0xFFFFFFFFu);
  }
}

// ===== K4: KNN (wave/point ILP-4) + BN1 moment partials =====
__global__ __launch_bounds__(512) void knn4_k(const float* __restrict__ f,
    const float* __restrict__ sval, const int* __restrict__ sidx,
    float* __restrict__ dout, double* __restrict__ part1) {
  const int tid = threadIdx.x, blk = blockIdx.x;   // 512 blocks
  const int l = tid & 63, w = tid >> 6;            // 8 waves
  const int bq = blk >> 7;                          // 128 blocks per batch
  const float* svb = sval + (bq << 12);
  const int*   sib = sidx + (bq << 12);
  const float* fB  = f + (bq << 12);
  double a0=0, a1=0, a2=0, a3=0, a4=0;
  unsigned long long kk[4];
  float fnp[4];
  int   sp[4];
#pragma unroll
  for (int p=0;p<4;p++) {
    int s = ((blk & 127) << 5) + (w << 2) + p;
    sp[p] = s;
    float fn = svb[s]; fnp[p] = fn;
    int start = s - 32;
    if (start < 0) start = 0;
    if (start > NPIX - 64) start = NPIX - 64;
    int q = start + l;
    float fm = svb[q];
    int   m  = sib[q];
    float sqn = __fmul_rn(fn, fn);
    float pr  = __fmul_rn(fn, fm);
    float dist = __fsub_rn(__fadd_rn(sqn, __fmul_rn(fm, fm)), __fmul_rn(2.0f, pr));
    unsigned u = __float_as_uint(dist);
    u ^= (u >> 31) ? 0xFFFFFFFFu : 0x80000000u;
    kk[p] = (((unsigned long long)u) << 32) | (unsigned)m;
  }
#pragma unroll
  for (int k = 2; k <= 64; k <<= 1)
#pragma unroll
    for (int j = k >> 1; j > 0; j >>= 1) {
#pragma unroll
      for (int p=0;p<4;p++) {
        unsigned long long pp = shflx64(kk[p], j);
        bool up = ((l & k) == 0);
        bool keepmin = ((l & j) == 0) == up;
        kk[p] = (keepmin ? (pp < kk[p]) : (pp > kk[p])) ? pp : kk[p];
      }
    }
#pragma unroll
  for (int p=0;p<4;p++) {
    int mr = (int)(kk[p] & 0xFFFFFFFFu);
    float fn = fnp[p];
    float d = __fsub_rn(fB[mr], fn);       // knn - x1, rank l
    int n = sib[sp[p]];
    if (l >= 1 && l <= 20)
      dout[(size_t)((bq<<12) + n)*KN + (l-1)] = d;
    float dm = (l >= 1 && l <= 20) ? d : 0.f;
    a2 += (double)dm;
    a3 += (double)dm * (double)dm;
    a4 += (double)fn * (double)dm;
    if (l == 0) { a0 += (double)fn; a1 += (double)fn * (double)fn; }
  }
  double v[5] = {a0, a1, a2, a3, a4};
#pragma unroll
  for (int qi=0; qi<5; qi++)
    for (int off=32; off>0; off>>=1) v[qi] += __shfl_down(v[qi], off, 64);
  __shared__ double sred[8][5];
  if (l == 0)
#pragma unroll
    for (int qi=0; qi<5; qi++) sred[w][qi] = v[qi];
  __syncthreads();
  if (tid == 0) {
#pragma unroll
    for (int qi=0; qi<5; qi++) {
      double s = 0.0;
#pragma unroll
      for (int ww=0; ww<8; ww++) s += sred[ww][qi];
      part1[blk*5 + qi] = s;
    }
  }
}

// ===== K5: redundant BN1 fold + per-branch o_pre max/min + BN2 partials =====
__global__ __launch_bounds__(64) void branch_k(const float* __restrict__ f,
    const float* __restrict__ dw, const double* __restrict__ part1,
    const float* __restrict__ ew1, const float* __restrict__ eb1,
    const float* __restrict__ eg1, const float* __restrict__ ebt1,
    const float* __restrict__ ew2, const float* __restrict__ eb2,
    float* __restrict__ maxo, float* __restrict__ mino,
    double* __restrict__ part2) {
  const int l = threadIdx.x;
  const int blk = blockIdx.x, br = blockIdx.y;
  double a[5] = {0,0,0,0,0};
  for (int b2 = l; b2 < 512; b2 += 64)
#pragma unroll
    for (int q=0;q<5;q++) a[q] += part1[b2*5+q];
#pragma unroll
  for (int q=0;q<5;q++)
    for (int off=32; off>0; off>>=1) a[q] += __shfl_down(a[q], off, 64);
#pragma unroll
  for (int q=0;q<5;q++) a[q] = __shfl(a[q], 0, 64);
  double Ef = a[0]/16384.0, Eff = a[1]/16384.0;
  double Ed = a[2]/MTOT, Edd = a[3]/MTOT, Efd = a[4]/MTOT;
  double Vf = Eff - Ef*Ef, Vd = Edd - Ed*Ed, Cfd = Efd - Ef*Ed;
  float sA[16], sB[16], sC[16], sW[16];
#pragma unroll
  for (int c=0;c<16;c++) {
    int idx = br*16 + c;
    double w0 = (double)ew1[idx*2+0], w1 = (double)ew1[idx*2+1];
    double b1 = (double)eb1[idx];
    double m1 = w0*Ef + w1*Ed + b1;
    double v1 = w0*w0*Vf + 2.0*w0*w1*Cfd + w1*w1*Vd;
    double r1 = 1.0 / sqrt(v1 + 1e-5);
    double g = (double)eg1[idx];
    sA[c] = (float)(g*r1*w0);
    sB[c] = (float)(g*r1*w1);
    sC[c] = (float)(g*r1*(b1 - m1) + (double)ebt1[idx]);
    sW[c] = ew2[idx];
  }
  int row = (blk << 6) + l;
  float fv = f[row];
  const float* dd = dw + (size_t)row*KN;
  float b2v = eb2[br];
  float P[16];
#pragma unroll
  for (int c=0;c<16;c++) P[c] = fmaf(sA[c], fv, sC[c]);
  float mx = -INFINITY, mn = INFINITY;
  double s = 0.0, s2 = 0.0;
  for (int k=0;k<KN;k++) {
    float d = dd[k];
    float t = b2v;
#pragma unroll
    for (int c=0;c<16;c++)
      t = fmaf(sW[c], fmaxf(fmaf(sB[c], d, P[c]), 0.f), t);
    mx = fmaxf(mx, t);
    mn = fminf(mn, t);
    double td = (double)t;
    s += td; s2 += td*td;
  }
  maxo[br*16384 + row] = mx;
  mino[br*16384 + row] = mn;
#pragma unroll
  for (int off=32; off>0; off>>=1) {
    s  += __shfl_down(s, off, 64);
    s2 += __shfl_down(s2, off, 64);
  }
  if (l == 0) {
    part2[(br*256 + blk)*2 + 0] = s;
    part2[(br*256 + blk)*2 + 1] = s2;
  }
}

// ===== K6: redundant BN2 fold + pixel shuffle + sigmoid =====
__global__ __launch_bounds__(256) void out_k(const float* __restrict__ f,
    const float* __restrict__ maxo, const float* __restrict__ mino,
    const double* __restrict__ part2,
    const float* __restrict__ eg2, const float* __restrict__ ebt2,
    float* __restrict__ out) {
  __shared__ float c2c[3][2];
  const int tid = threadIdx.x, blk = blockIdx.x;
  const int l = tid & 63, w = tid >> 6;
  if (w < 3) {
    int br = w;
    double s = 0.0, s2 = 0.0;
#pragma unroll
    for (int i=0;i<4;i++) {
      int bb = l + (i << 6);
      s  += part2[(br*256 + bb)*2 + 0];
      s2 += part2[(br*256 + bb)*2 + 1];
    }
#pragma unroll
    for (int off=32; off>0; off>>=1) {
      s  += __shfl_down(s, off, 64);
      s2 += __shfl_down(s2, off, 64);
    }
    if (l == 0) {
      double mean = s / MTOT;
      double var = s2 / MTOT - mean*mean;
      double r2 = 1.0 / sqrt(var + 1e-5);
      double sc = (double)eg2[br] * r2;
      c2c[br][0] = (float)sc;
      c2c[br][1] = (float)((double)ebt2[br] - sc*mean);
    }
  }
  __syncthreads();
  int tg = (blk << 8) + tid;     // 65536
  int bo = tg >> 14;
  int y = (tg >> 7) & 127, xx = tg & 127;
  int n = ((y>>1)<<6) + (xx>>1);
  int ch = ((y&1)<<1) + (xx&1);
  float v;
  if (ch == 0) {
    v = f[bo*NPIX + n];
  } else {
    int br = ch - 1;
    float sc = c2c[br][0], sh = c2c[br][1];
    float base = (sc >= 0.f) ? maxo[br*16384 + bo*NPIX + n]
                             : mino[br*16384 + bo*NPIX + n];
    v = fmaxf(fmaf(sc, base, sh), 0.f);
  }
  out[tg] = 1.f / (1.f + expf(-v));
}

extern "C" void kernel_launch(void* const* d_in, const int* in_sizes, int n_in,
                              void* d_out, int out_size, void* d_ws, size_t ws_size,
                              hipStream_t stream) {
  (void)in_sizes; (void)n_in; (void)out_size; (void)ws_size;
  const float* x    = (const float*)d_in[0];
  const float* c1w  = (const float*)d_in[1];
  const float* c1b  = (const float*)d_in[2];
  const float* c2w  = (const float*)d_in[3];
  const float* c2b  = (const float*)d_in[4];
  const float* c3w  = (const float*)d_in[5];
  const float* c3b  = (const float*)d_in[6];
  const float* c4w  = (const float*)d_in[7];
  const float* c4b  = (const float*)d_in[8];
  const float* ew1  = (const float*)d_in[9];
  const float* eb1  = (const float*)d_in[10];
  const float* eg1  = (const float*)d_in[11];
  const float* ebt1 = (const float*)d_in[12];
  const float* ew2  = (const float*)d_in[13];
  const float* eb2  = (const float*)d_in[14];
  const float* eg2  = (const float*)d_in[15];
  const float* ebt2 = (const float*)d_in[16];
  float* out = (float*)d_out;
  float* ws  = (float*)d_ws;

  float*  c2buf = ws;                       // 524288 floats
  float*  fbuf  = ws + 524288;              // 16384
  float*  dw    = ws + 540672;              // 327680
  float*  sval  = ws + 868352;              // 16384
  int*    sidx  = (int*)(ws + 884736);      // 16384
  float*  maxo  = ws + 901120;              // 49152
  float*  mino  = ws + 950272;              // 49152
  double* part1 = (double*)(ws + 999424);   // 512*5 doubles
  double* part2 = (double*)(ws + 1004544);  // 256*3*2 doubles

  conv12_k<<<dim3(4,64), 512, 0, stream>>>(x, c1w, c1b, c2w, c2b, c2buf);
  conv34_k<<<dim3(4,64), 512, 0, stream>>>(c2buf, c3w, c3b, c4w, c4b, fbuf);
  sort2_k<<<4, 1024, 0, stream>>>(fbuf, sval, sidx);
  knn4_k<<<512, 512, 0, stream>>>(fbuf, sval, sidx, dw, part1);
  branch_k<<<dim3(256,3), 64, 0, stream>>>(fbuf, dw, part1,
      ew1, eb1, eg1, ebt1, ew2, eb2, maxo, mino, part2);
  out_k<<<256, 256, 0, stream>>>(fbuf, maxo, mino, part2, eg2, ebt2, out);
}

// Round 15
// 118.414 us; speedup vs baseline: 1.0381x; 1.0381x over previous
//
#include <hip/hip_runtime.h>
#include <math.h>

#define NPIX 4096
#define KN 20
#define MTOT 327680.0    // B*N*K

__device__ inline unsigned long long shflx64(unsigned long long v, int m) {
  unsigned lo = (unsigned)v, hi = (unsigned)(v >> 32);
  lo = __shfl_xor(lo, m, 64);
  hi = __shfl_xor(hi, m, 64);
  return (((unsigned long long)hi) << 32) | lo;
}

// ===== K1: conv1 (5x5,1->64,tanh, zero-outside) + conv2 partial (3x3, cin-half) =====
// Grid (4,64,2): block z handles conv1 couts / conv2 cins z*32..z*32+31.
// 512 blocks -> 16 waves/CU (4/SIMD). Partials to global; conv34 fuses tanh(p0+p1).
__global__ __launch_bounds__(512) void conv12_k(const float* __restrict__ x,
    const float* __restrict__ c1w, const float* __restrict__ c1b,
    const float* __restrict__ c2w, const float* __restrict__ c2b,
    float* __restrict__ part12) {
  __shared__ float sx[224];          // 14x14 halo, stride 16
  __shared__ float sc1[3840];        // 32 local ch x (10x10 halo, stride-12 rows)
  __shared__ float red[4608];        // 8 waves x 64 px x 9 (8 couts + pad)
  const int tid = threadIdx.x;
  const int l = tid & 63;
  const int w = __builtin_amdgcn_readfirstlane(tid >> 6);   // 8 waves, uniform
  const int b = blockIdx.x, tile = blockIdx.y, z = blockIdx.z;
  const int th = (tile >> 3) << 3, tw = (tile & 7) << 3;

  for (int i = tid; i < 196; i += 512) {
    int r = i / 14, c = i - r*14;
    int gr = th - 3 + r, gc = tw - 3 + c;
    sx[r*16 + c] = (gr>=0 && gr<64 && gc>=0 && gc<64) ? x[b*NPIX + (gr<<6) + gc] : 0.f;
  }
  __syncthreads();
  // conv1 on 10x10 halo; wave w -> local couts w*4..+3 (global z*32 + lc)
  for (int half = 0; half < 2; half++) {
    int px = l + (half << 6);
    if (px < 100) {
      int i = px / 10, j = px - i*10;
      int gy = th - 1 + i, gx = tw - 1 + j;
      bool inb = (gy>=0 && gy<64 && gx>=0 && gx<64);
      for (int cc = 0; cc < 4; cc++) {
        int lc = (w << 2) + cc;
        int co = (z << 5) + lc;
        float acc = c1b[co];
#pragma unroll
        for (int di=0; di<5; di++)
#pragma unroll
          for (int dj=0; dj<5; dj++)
            acc = fmaf(sx[(i+di)*16 + j+dj], c1w[co*25 + di*5 + dj], acc);
        sc1[lc*120 + i*12 + j] = inb ? tanhf(acc) : 0.f;
      }
    }
  }
  __syncthreads();
  // conv2 partial: thread = pixel (l); wave w -> local cins w*4..+3; all 32 couts
  float acc[32];
  {
    int py = l >> 3, px2 = l & 7;
#pragma unroll
    for (int o=0;o<32;o++) acc[o] = (z == 0 && w == 0) ? c2b[o] : 0.f;
    for (int ci = 0; ci < 4; ci++) {
      int lc = (w << 2) + ci;
      int cin = (z << 5) + lc;
      const float* sp = sc1 + lc*120;
      float v[9];
#pragma unroll
      for (int di=0;di<3;di++)
#pragma unroll
        for (int dj=0;dj<3;dj++)
          v[di*3+dj] = sp[(py+di)*12 + px2+dj];
      const float* wc = c2w + cin*9;      // + co*576 per cout
#pragma unroll
      for (int o=0;o<32;o++) {
        const float* wo = wc + o*576;
#pragma unroll
        for (int t=0;t<9;t++)
          acc[o] = fmaf(v[t], wo[t], acc[o]);
      }
    }
  }
  // cross-wave reduction in 4 chunks of 8 couts; write partial to global
  {
    int py = l >> 3, px2 = l & 7;
    for (int ch = 0; ch < 4; ch++) {
      __syncthreads();
#pragma unroll
      for (int cc = 0; cc < 8; cc++)
        red[w*576 + l*9 + cc] = acc[(ch<<3) + cc];
      __syncthreads();
      float s = red[0*576 + l*9 + w];     // w doubles as cout-in-chunk (0..7)
#pragma unroll
      for (int ww=1; ww<8; ww++) s += red[ww*576 + l*9 + w];
      int co = (ch<<3) + w;
      part12[(((size_t)(z*4 + b)*32 + co) << 12) + ((th+py)<<6) + (tw+px2)] = s;
    }
  }
}

// ===== K2: conv3 (3x3,32->16,tanh, zero-outside) + conv4 (3x3,16->1) =====
// Staging fuses conv2 finalize: tanh(p0 + p1). conv3 cin-split across 4 groups.
__global__ __launch_bounds__(512) void conv34_k(const float* __restrict__ part12,
    const float* __restrict__ c3w, const float* __restrict__ c3b,
    const float* __restrict__ c4w, const float* __restrict__ c4b,
    float* __restrict__ fbuf) {
  __shared__ float sc2[4608];        // 32 ch x (12x12, stride-12 rows)
  __shared__ float sc3[1920];        // 16 ch x (10x10 halo, stride-12 rows)
  __shared__ float red[2000];        // 4 grp x 100 px x 5 (4 couts + pad)
  const int tid = threadIdx.x;
  const int b = blockIdx.x, tile = blockIdx.y;
  const int th = (tile >> 3) << 3, tw = (tile & 7) << 3;
  const int px = tid & 127;
  const int cinw = __builtin_amdgcn_readfirstlane(tid >> 7);  // 0..3, uniform

  for (int i = tid; i < 4608; i += 512) {
    int cin = i / 144, rem = i - cin*144;
    int rr = rem / 12, cc = rem - rr*12;
    int gr = th - 2 + rr, gc = tw - 2 + cc;
    float v = 0.f;
    if (gr>=0 && gr<64 && gc>=0 && gc<64) {
      size_t idx = (((size_t)b*32 + cin) << 12) + (gr<<6) + gc;
      v = tanhf(part12[idx] + part12[idx + 524288]);
    }
    sc2[cin*144 + rr*12 + cc] = v;
  }
  __syncthreads();
  float acc[16];
  int pi = px / 10, pj = px - pi*10;
  if (px < 100) {
#pragma unroll
    for (int o=0;o<16;o++) acc[o] = (cinw == 0) ? c3b[o] : 0.f;
    for (int ci = 0; ci < 8; ci++) {
      int cin = (cinw << 3) + ci;
      const float* sp = sc2 + cin*144;
      float v[9];
#pragma unroll
      for (int di=0;di<3;di++)
#pragma unroll
        for (int dj=0;dj<3;dj++)
          v[di*3+dj] = sp[(pi+di)*12 + pj+dj];
      const float* wc = c3w + cin*9;      // + co*288 per cout
#pragma unroll
      for (int o=0;o<16;o++) {
        const float* wo = wc + o*288;
#pragma unroll
        for (int t=0;t<9;t++)
          acc[o] = fmaf(v[t], wo[t], acc[o]);
      }
    }
  }
  int gy = th - 1 + pi, gx = tw - 1 + pj;
  bool inb = (gy>=0 && gy<64 && gx>=0 && gx<64);
  for (int ch = 0; ch < 4; ch++) {
    __syncthreads();
    if (px < 100) {
#pragma unroll
      for (int cc = 0; cc < 4; cc++)
        red[cinw*500 + px*5 + cc] = acc[(ch<<2) + cc];
    }
    __syncthreads();
    if (px < 100) {
      float s = red[0*500 + px*5 + cinw];  // cinw doubles as cout-in-chunk
#pragma unroll
      for (int g=1; g<4; g++) s += red[g*500 + px*5 + cinw];
      int co = (ch<<2) + cinw;
      sc3[co*120 + pi*12 + pj] = inb ? tanhf(s) : 0.f;
    }
  }
  __syncthreads();
  if (tid < 64) {
    int py = tid >> 3, qx = tid & 7;
    float acc4 = c4b[0];
    for (int cin = 0; cin < 16; cin++) {
#pragma unroll
      for (int di=0;di<3;di++)
#pragma unroll
        for (int dj=0;dj<3;dj++)
          acc4 = fmaf(sc3[cin*120 + (py+di)*12 + qx+dj], c4w[cin*9 + di*3+dj], acc4);
    }
    fbuf[b*NPIX + ((th+py)<<6) + (tw+qx)] = acc4;
  }
}

// ===== K3: per-batch sort: wave bitonic (256-runs) + merge-path =====
__global__ __launch_bounds__(1024) void sort2_k(const float* __restrict__ f,
    float* __restrict__ sval, int* __restrict__ sidx) {
  int b = blockIdx.x;
  int tid = threadIdx.x;
  int l = tid & 63, w = tid >> 6;
  __shared__ unsigned long long Ab[NPIX];
  __shared__ unsigned long long Bb[NPIX];
  const float* fb = f + b*NPIX;
  unsigned long long key[4];
#pragma unroll
  for (int r=0;r<4;r++) {
    unsigned e = (w<<8) + (r<<6) + l;
    float v = fb[e];
    unsigned u = __float_as_uint(v);
    u ^= (u >> 31) ? 0xFFFFFFFFu : 0x80000000u;   // order-preserving flip
    key[r] = (((unsigned long long)u) << 32) | e;
  }
  for (unsigned k = 2; k <= 256; k <<= 1) {
    for (unsigned j = k >> 1; j > 0; j >>= 1) {
      if (j >= 64) {
        unsigned rj = j >> 6;
#pragma unroll
        for (int r=0;r<4;r++) {
          int pr = r ^ (int)rj;
          if (pr > r) {
            unsigned e = (w<<8)+((unsigned)r<<6)+l;
            bool up = ((e & k & 255u) == 0);
            unsigned long long a = key[r], c = key[pr];
            bool sw = up ? (c < a) : (c > a);
            if (sw) { key[r] = c; key[pr] = a; }
          }
        }
      } else {
#pragma unroll
        for (int r=0;r<4;r++) {
          unsigned e = (w<<8)+((unsigned)r<<6)+l;
          unsigned long long a = key[r];
          unsigned long long p = shflx64(a, (int)j);
          bool up = ((e & k & 255u) == 0);
          bool keepmin = ((e & j) == 0) == up;
          key[r] = (keepmin ? (p < a) : (p > a)) ? p : a;
        }
      }
    }
  }
#pragma unroll
  for (int r=0;r<4;r++) Ab[(w<<8)+(r<<6)+l] = key[r];
  __syncthreads();
  unsigned long long* src = Ab;
  unsigned long long* dst = Bb;
  for (int lg = 8; lg <= 11; lg++) {
    const int L = 1 << lg;
    int p0 = tid << 2;
    int ri = p0 >> lg;
    int base = (ri ^ 1) << lg;
    int mbase = ((ri >> 1) << (lg + 1)) + (p0 & (L - 1));
    unsigned long long kk[4];
    int lo[4], hi[4];
#pragma unroll
    for (int r=0;r<4;r++) { kk[r] = src[p0 + r]; lo[r] = 0; hi[r] = L; }
    for (int s = 0; s <= lg; s++) {
#pragma unroll
      for (int r=0;r<4;r++) {
        if (lo[r] < hi[r]) {
          int mid = (lo[r] + hi[r]) >> 1;
          if (src[base + mid] < kk[r]) lo[r] = mid + 1; else hi[r] = mid;
        }
      }
    }
#pragma unroll
    for (int r=0;r<4;r++) dst[mbase + r + lo[r]] = kk[r];
    __syncthreads();
    unsigned long long* t = src; src = dst; dst = t;
  }
#pragma unroll
  for (int r=0;r<4;r++) {
    int p = (tid << 2) + r;
    unsigned long long kk = src[p];
    unsigned u = (unsigned)(kk >> 32);
    u ^= (u >> 31) ? 0x80000000u : 0xFFFFFFFFu;   // un-flip
    sval[b*NPIX + p] = __uint_as_float(u);
    sidx[b*NPIX + p] = (int)(kk & 0xFFFFFFFFu);
  }
}

// ===== K4: KNN (wave/point ILP-4) + BN1 moment partials =====
__global__ __launch_bounds__(512) void knn4_k(const float* __restrict__ f,
    const float* __restrict__ sval, const int* __restrict__ sidx,
    float* __restrict__ dout, double* __restrict__ part1) {
  const int tid = threadIdx.x, blk = blockIdx.x;   // 512 blocks
  const int l = tid & 63, w = tid >> 6;            // 8 waves
  const int bq = blk >> 7;                          // 128 blocks per batch
  const float* svb = sval + (bq << 12);
  const int*   sib = sidx + (bq << 12);
  const float* fB  = f + (bq << 12);
  double a0=0, a1=0, a2=0, a3=0, a4=0;
  unsigned long long kk[4];
  float fnp[4];
  int   sp[4];
#pragma unroll
  for (int p=0;p<4;p++) {
    int s = ((blk & 127) << 5) + (w << 2) + p;
    sp[p] = s;
    float fn = svb[s]; fnp[p] = fn;
    int start = s - 32;
    if (start < 0) start = 0;
    if (start > NPIX - 64) start = NPIX - 64;
    int q = start + l;
    float fm = svb[q];
    int   m  = sib[q];
    float sqn = __fmul_rn(fn, fn);
    float pr  = __fmul_rn(fn, fm);
    float dist = __fsub_rn(__fadd_rn(sqn, __fmul_rn(fm, fm)), __fmul_rn(2.0f, pr));
    unsigned u = __float_as_uint(dist);
    u ^= (u >> 31) ? 0xFFFFFFFFu : 0x80000000u;
    kk[p] = (((unsigned long long)u) << 32) | (unsigned)m;
  }
#pragma unroll
  for (int k = 2; k <= 64; k <<= 1)
#pragma unroll
    for (int j = k >> 1; j > 0; j >>= 1) {
#pragma unroll
      for (int p=0;p<4;p++) {
        unsigned long long pp = shflx64(kk[p], j);
        bool up = ((l & k) == 0);
        bool keepmin = ((l & j) == 0) == up;
        kk[p] = (keepmin ? (pp < kk[p]) : (pp > kk[p])) ? pp : kk[p];
      }
    }
#pragma unroll
  for (int p=0;p<4;p++) {
    int mr = (int)(kk[p] & 0xFFFFFFFFu);
    float fn = fnp[p];
    float d = __fsub_rn(fB[mr], fn);       // knn - x1, rank l
    int n = sib[sp[p]];
    if (l >= 1 && l <= 20)
      dout[(size_t)((bq<<12) + n)*KN + (l-1)] = d;
    float dm = (l >= 1 && l <= 20) ? d : 0.f;
    a2 += (double)dm;
    a3 += (double)dm * (double)dm;
    a4 += (double)fn * (double)dm;
    if (l == 0) { a0 += (double)fn; a1 += (double)fn * (double)fn; }
  }
  double v[5] = {a0, a1, a2, a3, a4};
#pragma unroll
  for (int qi=0; qi<5; qi++)
    for (int off=32; off>0; off>>=1) v[qi] += __shfl_down(v[qi], off, 64);
  __shared__ double sred[8][5];
  if (l == 0)
#pragma unroll
    for (int qi=0; qi<5; qi++) sred[w][qi] = v[qi];
  __syncthreads();
  if (tid == 0) {
#pragma unroll
    for (int qi=0; qi<5; qi++) {
      double s = 0.0;
#pragma unroll
      for (int ww=0; ww<8; ww++) s += sred[ww][qi];
      part1[blk*5 + qi] = s;
    }
  }
}

// ===== K5: redundant BN1 fold + per-branch o_pre max/min + BN2 partials =====
__global__ __launch_bounds__(64) void branch_k(const float* __restrict__ f,
    const float* __restrict__ dw, const double* __restrict__ part1,
    const float* __restrict__ ew1, const float* __restrict__ eb1,
    const float* __restrict__ eg1, const float* __restrict__ ebt1,
    const float* __restrict__ ew2, const float* __restrict__ eb2,
    float* __restrict__ maxo, float* __restrict__ mino,
    double* __restrict__ part2) {
  const int l = threadIdx.x;
  const int blk = blockIdx.x, br = blockIdx.y;
  double a[5] = {0,0,0,0,0};
  for (int b2 = l; b2 < 512; b2 += 64)
#pragma unroll
    for (int q=0;q<5;q++) a[q] += part1[b2*5+q];
#pragma unroll
  for (int q=0;q<5;q++)
    for (int off=32; off>0; off>>=1) a[q] += __shfl_down(a[q], off, 64);
#pragma unroll
  for (int q=0;q<5;q++) a[q] = __shfl(a[q], 0, 64);
  double Ef = a[0]/16384.0, Eff = a[1]/16384.0;
  double Ed = a[2]/MTOT, Edd = a[3]/MTOT, Efd = a[4]/MTOT;
  double Vf = Eff - Ef*Ef, Vd = Edd - Ed*Ed, Cfd = Efd - Ef*Ed;
  float sA[16], sB[16], sC[16], sW[16];
#pragma unroll
  for (int c=0;c<16;c++) {
    int idx = br*16 + c;
    double w0 = (double)ew1[idx*2+0], w1 = (double)ew1[idx*2+1];
    double b1 = (double)eb1[idx];
    double m1 = w0*Ef + w1*Ed + b1;
    double v1 = w0*w0*Vf + 2.0*w0*w1*Cfd + w1*w1*Vd;
    double r1 = 1.0 / sqrt(v1 + 1e-5);
    double g = (double)eg1[idx];
    sA[c] = (float)(g*r1*w0);
    sB[c] = (float)(g*r1*w1);
    sC[c] = (float)(g*r1*(b1 - m1) + (double)ebt1[idx]);
    sW[c] = ew2[idx];
  }
  int row = (blk << 6) + l;
  float fv = f[row];
  const float* dd = dw + (size_t)row*KN;
  float b2v = eb2[br];
  float P[16];
#pragma unroll
  for (int c=0;c<16;c++) P[c] = fmaf(sA[c], fv, sC[c]);
  float mx = -INFINITY, mn = INFINITY;
  double s = 0.0, s2 = 0.0;
  for (int k=0;k<KN;k++) {
    float d = dd[k];
    float t = b2v;
#pragma unroll
    for (int c=0;c<16;c++)
      t = fmaf(sW[c], fmaxf(fmaf(sB[c], d, P[c]), 0.f), t);
    mx = fmaxf(mx, t);
    mn = fminf(mn, t);
    double td = (double)t;
    s += td; s2 += td*td;
  }
  maxo[br*16384 + row] = mx;
  mino[br*16384 + row] = mn;
#pragma unroll
  for (int off=32; off>0; off>>=1) {
    s  += __shfl_down(s, off, 64);
    s2 += __shfl_down(s2, off, 64);
  }
  if (l == 0) {
    part2[(br*256 + blk)*2 + 0] = s;
    part2[(br*256 + blk)*2 + 1] = s2;
  }
}

// ===== K6: redundant BN2 fold + pixel shuffle + sigmoid =====
__global__ __launch_bounds__(256) void out_k(const float* __restrict__ f,
    const float* __restrict__ maxo, const float* __restrict__ mino,
    const double* __restrict__ part2,
    const float* __restrict__ eg2, const float* __restrict__ ebt2,
    float* __restrict__ out) {
  __shared__ float c2c[3][2];
  const int tid = threadIdx.x, blk = blockIdx.x;
  const int l = tid & 63, w = tid >> 6;
  if (w < 3) {
    int br = w;
    double s = 0.0, s2 = 0.0;
#pragma unroll
    for (int i=0;i<4;i++) {
      int bb = l + (i << 6);
      s  += part2[(br*256 + bb)*2 + 0];
      s2 += part2[(br*256 + bb)*2 + 1];
    }
#pragma unroll
    for (int off=32; off>0; off>>=1) {
      s  += __shfl_down(s, off, 64);
      s2 += __shfl_down(s2, off, 64);
    }
    if (l == 0) {
      double mean = s / MTOT;
      double var = s2 / MTOT - mean*mean;
      double r2 = 1.0 / sqrt(var + 1e-5);
      double sc = (double)eg2[br] * r2;
      c2c[br][0] = (float)sc;
      c2c[br][1] = (float)((double)ebt2[br] - sc*mean);
    }
  }
  __syncthreads();
  int tg = (blk << 8) + tid;     // 65536
  int bo = tg >> 14;
  int y = (tg >> 7) & 127, xx = tg & 127;
  int n = ((y>>1)<<6) + (xx>>1);
  int ch = ((y&1)<<1) + (xx&1);
  float v;
  if (ch == 0) {
    v = f[bo*NPIX + n];
  } else {
    int br = ch - 1;
    float sc = c2c[br][0], sh = c2c[br][1];
    float base = (sc >= 0.f) ? maxo[br*16384 + bo*NPIX + n]
                             : mino[br*16384 + bo*NPIX + n];
    v = fmaxf(fmaf(sc, base, sh), 0.f);
  }
  out[tg] = 1.f / (1.f + expf(-v));
}

extern "C" void kernel_launch(void* const* d_in, const int* in_sizes, int n_in,
                              void* d_out, int out_size, void* d_ws, size_t ws_size,
                              hipStream_t stream) {
  (void)in_sizes; (void)n_in; (void)out_size; (void)ws_size;
  const float* x    = (const float*)d_in[0];
  const float* c1w  = (const float*)d_in[1];
  const float* c1b  = (const float*)d_in[2];
  const float* c2w  = (const float*)d_in[3];
  const float* c2b  = (const float*)d_in[4];
  const float* c3w  = (const float*)d_in[5];
  const float* c3b  = (const float*)d_in[6];
  const float* c4w  = (const float*)d_in[7];
  const float* c4b  = (const float*)d_in[8];
  const float* ew1  = (const float*)d_in[9];
  const float* eb1  = (const float*)d_in[10];
  const float* eg1  = (const float*)d_in[11];
  const float* ebt1 = (const float*)d_in[12];
  const float* ew2  = (const float*)d_in[13];
  const float* eb2  = (const float*)d_in[14];
  const float* eg2  = (const float*)d_in[15];
  const float* ebt2 = (const float*)d_in[16];
  float* out = (float*)d_out;
  float* ws  = (float*)d_ws;

  float*  part12 = ws;                       // 1048576 floats (2 x 4 x 32 x 4096)
  float*  fbuf  = ws + 1048576;              // 16384
  float*  dw    = ws + 1064960;              // 327680
  float*  sval  = ws + 1392640;              // 16384
  int*    sidx  = (int*)(ws + 1409024);      // 16384
  float*  maxo  = ws + 1425408;              // 49152
  float*  mino  = ws + 1474560;              // 49152
  double* part1 = (double*)(ws + 1523712);   // 512*5 doubles
  double* part2 = (double*)(ws + 1528832);   // 256*3*2 doubles

  conv12_k<<<dim3(4,64,2), 512, 0, stream>>>(x, c1w, c1b, c2w, c2b, part12);
  conv34_k<<<dim3(4,64), 512, 0, stream>>>(part12, c3w, c3b, c4w, c4b, fbuf);
  sort2_k<<<4, 1024, 0, stream>>>(fbuf, sval, sidx);
  knn4_k<<<512, 512, 0, stream>>>(fbuf, sval, sidx, dw, part1);
  branch_k<<<dim3(256,3), 64, 0, stream>>>(fbuf, dw, part1,
      ew1, eb1, eg1, ebt1, ew2, eb2, maxo, mino, part2);
  out_k<<<256, 256, 0, stream>>>(fbuf, maxo, mino, part2, eg2, ebt2, out);
}

// Round 16
// 114.519 us; speedup vs baseline: 1.0734x; 1.0340x over previous
//
#include <hip/hip_runtime.h>
#include <math.h>

#define NPIX 4096
#define KN 20
#define MTOT 327680.0    // B*N*K

__device__ inline unsigned long long shflx64(unsigned long long v, int m) {
  unsigned lo = (unsigned)v, hi = (unsigned)(v >> 32);
  lo = __shfl_xor(lo, m, 64);
  hi = __shfl_xor(hi, m, 64);
  return (((unsigned long long)hi) << 32) | lo;
}

// ===== K1: conv1 (5x5,1->64,tanh, zero-outside) + conv2 partial (3x3, cin-quarter) =====
// Grid (4,64,4): block z handles conv1 couts / conv2 cins z*16..z*16+15.
// 1024 blocks, 27KB LDS -> 4 blocks/CU x 8 waves = 32 waves/CU (max occupancy).
__global__ __launch_bounds__(512) void conv12_k(const float* __restrict__ x,
    const float* __restrict__ c1w, const float* __restrict__ c1b,
    const float* __restrict__ c2w, const float* __restrict__ c2b,
    float* __restrict__ part12) {
  __shared__ float sx[224];          // 14x14 halo, stride 16
  __shared__ float sc1[1920];        // 16 local ch x (10x10 halo, stride-12 rows)
  __shared__ float red[4608];        // 8 waves x 64 px x 9 (8 couts + pad)
  const int tid = threadIdx.x;
  const int l = tid & 63;
  const int w = __builtin_amdgcn_readfirstlane(tid >> 6);   // 8 waves, uniform
  const int b = blockIdx.x, tile = blockIdx.y, z = blockIdx.z;
  const int th = (tile >> 3) << 3, tw = (tile & 7) << 3;

  for (int i = tid; i < 196; i += 512) {
    int r = i / 14, c = i - r*14;
    int gr = th - 3 + r, gc = tw - 3 + c;
    sx[r*16 + c] = (gr>=0 && gr<64 && gc>=0 && gc<64) ? x[b*NPIX + (gr<<6) + gc] : 0.f;
  }
  __syncthreads();
  // conv1 on 10x10 halo; wave w -> local couts w*2..+1 (global z*16 + lc)
  for (int half = 0; half < 2; half++) {
    int px = l + (half << 6);
    if (px < 100) {
      int i = px / 10, j = px - i*10;
      int gy = th - 1 + i, gx = tw - 1 + j;
      bool inb = (gy>=0 && gy<64 && gx>=0 && gx<64);
      for (int cc = 0; cc < 2; cc++) {
        int lc = (w << 1) + cc;
        int co = (z << 4) + lc;
        float acc = c1b[co];
#pragma unroll
        for (int di=0; di<5; di++)
#pragma unroll
          for (int dj=0; dj<5; dj++)
            acc = fmaf(sx[(i+di)*16 + j+dj], c1w[co*25 + di*5 + dj], acc);
        sc1[lc*120 + i*12 + j] = inb ? tanhf(acc) : 0.f;
      }
    }
  }
  __syncthreads();
  // conv2 partial: thread = pixel (l); wave w -> local cins w*2..+1; all 32 couts
  float acc[32];
  {
    int py = l >> 3, px2 = l & 7;
#pragma unroll
    for (int o=0;o<32;o++) acc[o] = (z == 0 && w == 0) ? c2b[o] : 0.f;
    for (int ci = 0; ci < 2; ci++) {
      int lc = (w << 1) + ci;
      int cin = (z << 4) + lc;
      const float* sp = sc1 + lc*120;
      float v[9];
#pragma unroll
      for (int di=0;di<3;di++)
#pragma unroll
        for (int dj=0;dj<3;dj++)
          v[di*3+dj] = sp[(py+di)*12 + px2+dj];
      const float* wc = c2w + cin*9;      // + co*576 per cout
#pragma unroll
      for (int o=0;o<32;o++) {
        const float* wo = wc + o*576;
#pragma unroll
        for (int t=0;t<9;t++)
          acc[o] = fmaf(v[t], wo[t], acc[o]);
      }
    }
  }
  // cross-wave reduction in 4 chunks of 8 couts; write partial to global
  {
    int py = l >> 3, px2 = l & 7;
    for (int ch = 0; ch < 4; ch++) {
      __syncthreads();
#pragma unroll
      for (int cc = 0; cc < 8; cc++)
        red[w*576 + l*9 + cc] = acc[(ch<<3) + cc];
      __syncthreads();
      float s = red[0*576 + l*9 + w];     // w doubles as cout-in-chunk (0..7)
#pragma unroll
      for (int ww=1; ww<8; ww++) s += red[ww*576 + l*9 + w];
      int co = (ch<<3) + w;
      part12[(((size_t)(z*4 + b)*32 + co) << 12) + ((th+py)<<6) + (tw+px2)] = s;
    }
  }
}

// ===== K2: conv3 (3x3,32->16,tanh, zero-outside) + conv4 (3x3,16->1) =====
// 4x8 tile (grid 4x128 = 512 blocks -> 16 waves/CU). Staging fuses conv2
// finalize tanh(p0+p1+p2+p3). conv3 cin-split across 4 groups (order as before).
__global__ __launch_bounds__(512) void conv34_k(const float* __restrict__ part12,
    const float* __restrict__ c3w, const float* __restrict__ c3b,
    const float* __restrict__ c4w, const float* __restrict__ c4b,
    float* __restrict__ fbuf) {
  __shared__ float sc2[3328];        // 32 ch x (8 x 12, stride 13)
  __shared__ float sc3[1248];        // 16 ch x (6 x 10 halo, stride 13)
  __shared__ float red[1200];        // 4 grp x 60 px x 5 (4 couts + pad)
  const int tid = threadIdx.x;
  const int b = blockIdx.x, tile = blockIdx.y;
  const int th = (tile >> 3) << 2, tw = (tile & 7) << 3;   // 16 row-tiles x 8 col-tiles
  const int px = tid & 127;
  const int cinw = __builtin_amdgcn_readfirstlane(tid >> 7);  // 0..3, uniform

  for (int i = tid; i < 3072; i += 512) {
    int cin = i / 96, rem = i - cin*96;
    int rr = rem / 12, cc = rem - rr*12;
    int gr = th - 2 + rr, gc = tw - 2 + cc;
    float v = 0.f;
    if (gr>=0 && gr<64 && gc>=0 && gc<64) {
      size_t idx = (((size_t)b*32 + cin) << 12) + (gr<<6) + gc;
      v = tanhf(part12[idx] + part12[idx + 524288] +
                part12[idx + 1048576] + part12[idx + 1572864]);
    }
    sc2[cin*104 + rr*13 + cc] = v;
  }
  __syncthreads();
  float acc[16];
  int pi = px / 10, pj = px - pi*10;     // halo 6x10
  if (px < 60) {
#pragma unroll
    for (int o=0;o<16;o++) acc[o] = (cinw == 0) ? c3b[o] : 0.f;
    for (int ci = 0; ci < 8; ci++) {
      int cin = (cinw << 3) + ci;
      const float* sp = sc2 + cin*104;
      float v[9];
#pragma unroll
      for (int di=0;di<3;di++)
#pragma unroll
        for (int dj=0;dj<3;dj++)
          v[di*3+dj] = sp[(pi+di)*13 + pj+dj];
      const float* wc = c3w + cin*9;      // + co*288 per cout
#pragma unroll
      for (int o=0;o<16;o++) {
        const float* wo = wc + o*288;
#pragma unroll
        for (int t=0;t<9;t++)
          acc[o] = fmaf(v[t], wo[t], acc[o]);
      }
    }
  }
  int gy = th - 1 + pi, gx = tw - 1 + pj;
  bool inb = (gy>=0 && gy<64 && gx>=0 && gx<64);
  for (int ch = 0; ch < 4; ch++) {
    __syncthreads();
    if (px < 60) {
#pragma unroll
      for (int cc = 0; cc < 4; cc++)
        red[cinw*300 + px*5 + cc] = acc[(ch<<2) + cc];
    }
    __syncthreads();
    if (px < 60) {
      float s = red[0*300 + px*5 + cinw];  // cinw doubles as cout-in-chunk
#pragma unroll
      for (int g=1; g<4; g++) s += red[g*300 + px*5 + cinw];
      int co = (ch<<2) + cinw;
      sc3[co*78 + pi*13 + pj] = inb ? tanhf(s) : 0.f;
    }
  }
  __syncthreads();
  if (tid < 32) {
    int py = tid >> 3, qx = tid & 7;     // 4x8 outputs
    float acc4 = c4b[0];
    for (int cin = 0; cin < 16; cin++) {
#pragma unroll
      for (int di=0;di<3;di++)
#pragma unroll
        for (int dj=0;dj<3;dj++)
          acc4 = fmaf(sc3[cin*78 + (py+di)*13 + qx+dj], c4w[cin*9 + di*3+dj], acc4);
    }
    fbuf[b*NPIX + ((th+py)<<6) + (tw+qx)] = acc4;
  }
}

// ===== K3: per-batch sort: wave bitonic (256-runs) + merge-path =====
__global__ __launch_bounds__(1024) void sort2_k(const float* __restrict__ f,
    float* __restrict__ sval, int* __restrict__ sidx) {
  int b = blockIdx.x;
  int tid = threadIdx.x;
  int l = tid & 63, w = tid >> 6;
  __shared__ unsigned long long Ab[NPIX];
  __shared__ unsigned long long Bb[NPIX];
  const float* fb = f + b*NPIX;
  unsigned long long key[4];
#pragma unroll
  for (int r=0;r<4;r++) {
    unsigned e = (w<<8) + (r<<6) + l;
    float v = fb[e];
    unsigned u = __float_as_uint(v);
    u ^= (u >> 31) ? 0xFFFFFFFFu : 0x80000000u;   // order-preserving flip
    key[r] = (((unsigned long long)u) << 32) | e;
  }
  for (unsigned k = 2; k <= 256; k <<= 1) {
    for (unsigned j = k >> 1; j > 0; j >>= 1) {
      if (j >= 64) {
        unsigned rj = j >> 6;
#pragma unroll
        for (int r=0;r<4;r++) {
          int pr = r ^ (int)rj;
          if (pr > r) {
            unsigned e = (w<<8)+((unsigned)r<<6)+l;
            bool up = ((e & k & 255u) == 0);
            unsigned long long a = key[r], c = key[pr];
            bool sw = up ? (c < a) : (c > a);
            if (sw) { key[r] = c; key[pr] = a; }
          }
        }
      } else {
#pragma unroll
        for (int r=0;r<4;r++) {
          unsigned e = (w<<8)+((unsigned)r<<6)+l;
          unsigned long long a = key[r];
          unsigned long long p = shflx64(a, (int)j);
          bool up = ((e & k & 255u) == 0);
          bool keepmin = ((e & j) == 0) == up;
          key[r] = (keepmin ? (p < a) : (p > a)) ? p : a;
        }
      }
    }
  }
#pragma unroll
  for (int r=0;r<4;r++) Ab[(w<<8)+(r<<6)+l] = key[r];
  __syncthreads();
  unsigned long long* src = Ab;
  unsigned long long* dst = Bb;
  for (int lg = 8; lg <= 11; lg++) {
    const int L = 1 << lg;
    int p0 = tid << 2;
    int ri = p0 >> lg;
    int base = (ri ^ 1) << lg;
    int mbase = ((ri >> 1) << (lg + 1)) + (p0 & (L - 1));
    unsigned long long kk[4];
    int lo[4], hi[4];
#pragma unroll
    for (int r=0;r<4;r++) { kk[r] = src[p0 + r]; lo[r] = 0; hi[r] = L; }
    for (int s = 0; s <= lg; s++) {
#pragma unroll
      for (int r=0;r<4;r++) {
        if (lo[r] < hi[r]) {
          int mid = (lo[r] + hi[r]) >> 1;
          if (src[base + mid] < kk[r]) lo[r] = mid + 1; else hi[r] = mid;
        }
      }
    }
#pragma unroll
    for (int r=0;r<4;r++) dst[mbase + r + lo[r]] = kk[r];
    __syncthreads();
    unsigned long long* t = src; src = dst; dst = t;
  }
#pragma unroll
  for (int r=0;r<4;r++) {
    int p = (tid << 2) + r;
    unsigned long long kk = src[p];
    unsigned u = (unsigned)(kk >> 32);
    u ^= (u >> 31) ? 0x80000000u : 0xFFFFFFFFu;   // un-flip
    sval[b*NPIX + p] = __uint_as_float(u);
    sidx[b*NPIX + p] = (int)(kk & 0xFFFFFFFFu);
  }
}

// ===== K4: KNN (wave/point ILP-4) + BN1 moment partials =====
__global__ __launch_bounds__(512) void knn4_k(const float* __restrict__ f,
    const float* __restrict__ sval, const int* __restrict__ sidx,
    float* __restrict__ dout, double* __restrict__ part1) {
  const int tid = threadIdx.x, blk = blockIdx.x;   // 512 blocks
  const int l = tid & 63, w = tid >> 6;            // 8 waves
  const int bq = blk >> 7;                          // 128 blocks per batch
  const float* svb = sval + (bq << 12);
  const int*   sib = sidx + (bq << 12);
  const float* fB  = f + (bq << 12);
  double a0=0, a1=0, a2=0, a3=0, a4=0;
  unsigned long long kk[4];
  float fnp[4];
  int   sp[4];
#pragma unroll
  for (int p=0;p<4;p++) {
    int s = ((blk & 127) << 5) + (w << 2) + p;
    sp[p] = s;
    float fn = svb[s]; fnp[p] = fn;
    int start = s - 32;
    if (start < 0) start = 0;
    if (start > NPIX - 64) start = NPIX - 64;
    int q = start + l;
    float fm = svb[q];
    int   m  = sib[q];
    float sqn = __fmul_rn(fn, fn);
    float pr  = __fmul_rn(fn, fm);
    float dist = __fsub_rn(__fadd_rn(sqn, __fmul_rn(fm, fm)), __fmul_rn(2.0f, pr));
    unsigned u = __float_as_uint(dist);
    u ^= (u >> 31) ? 0xFFFFFFFFu : 0x80000000u;
    kk[p] = (((unsigned long long)u) << 32) | (unsigned)m;
  }
#pragma unroll
  for (int k = 2; k <= 64; k <<= 1)
#pragma unroll
    for (int j = k >> 1; j > 0; j >>= 1) {
#pragma unroll
      for (int p=0;p<4;p++) {
        unsigned long long pp = shflx64(kk[p], j);
        bool up = ((l & k) == 0);
        bool keepmin = ((l & j) == 0) == up;
        kk[p] = (keepmin ? (pp < kk[p]) : (pp > kk[p])) ? pp : kk[p];
      }
    }
#pragma unroll
  for (int p=0;p<4;p++) {
    int mr = (int)(kk[p] & 0xFFFFFFFFu);
    float fn = fnp[p];
    float d = __fsub_rn(fB[mr], fn);       // knn - x1, rank l
    int n = sib[sp[p]];
    if (l >= 1 && l <= 20)
      dout[(size_t)((bq<<12) + n)*KN + (l-1)] = d;
    float dm = (l >= 1 && l <= 20) ? d : 0.f;
    a2 += (double)dm;
    a3 += (double)dm * (double)dm;
    a4 += (double)fn * (double)dm;
    if (l == 0) { a0 += (double)fn; a1 += (double)fn * (double)fn; }
  }
  double v[5] = {a0, a1, a2, a3, a4};
#pragma unroll
  for (int qi=0; qi<5; qi++)
    for (int off=32; off>0; off>>=1) v[qi] += __shfl_down(v[qi], off, 64);
  __shared__ double sred[8][5];
  if (l == 0)
#pragma unroll
    for (int qi=0; qi<5; qi++) sred[w][qi] = v[qi];
  __syncthreads();
  if (tid == 0) {
#pragma unroll
    for (int qi=0; qi<5; qi++) {
      double s = 0.0;
#pragma unroll
      for (int ww=0; ww<8; ww++) s += sred[ww][qi];
      part1[blk*5 + qi] = s;
    }
  }
}

// ===== K5: redundant BN1 fold + per-branch o_pre max/min + BN2 partials =====
__global__ __launch_bounds__(64) void branch_k(const float* __restrict__ f,
    const float* __restrict__ dw, const double* __restrict__ part1,
    const float* __restrict__ ew1, const float* __restrict__ eb1,
    const float* __restrict__ eg1, const float* __restrict__ ebt1,
    const float* __restrict__ ew2, const float* __restrict__ eb2,
    float* __restrict__ maxo, float* __restrict__ mino,
    double* __restrict__ part2) {
  const int l = threadIdx.x;
  const int blk = blockIdx.x, br = blockIdx.y;
  double a[5] = {0,0,0,0,0};
  for (int b2 = l; b2 < 512; b2 += 64)
#pragma unroll
    for (int q=0;q<5;q++) a[q] += part1[b2*5+q];
#pragma unroll
  for (int q=0;q<5;q++)
    for (int off=32; off>0; off>>=1) a[q] += __shfl_down(a[q], off, 64);
#pragma unroll
  for (int q=0;q<5;q++) a[q] = __shfl(a[q], 0, 64);
  double Ef = a[0]/16384.0, Eff = a[1]/16384.0;
  double Ed = a[2]/MTOT, Edd = a[3]/MTOT, Efd = a[4]/MTOT;
  double Vf = Eff - Ef*Ef, Vd = Edd - Ed*Ed, Cfd = Efd - Ef*Ed;
  float sA[16], sB[16], sC[16], sW[16];
#pragma unroll
  for (int c=0;c<16;c++) {
    int idx = br*16 + c;
    double w0 = (double)ew1[idx*2+0], w1 = (double)ew1[idx*2+1];
    double b1 = (double)eb1[idx];
    double m1 = w0*Ef + w1*Ed + b1;
    double v1 = w0*w0*Vf + 2.0*w0*w1*Cfd + w1*w1*Vd;
    double r1 = 1.0 / sqrt(v1 + 1e-5);
    double g = (double)eg1[idx];
    sA[c] = (float)(g*r1*w0);
    sB[c] = (float)(g*r1*w1);
    sC[c] = (float)(g*r1*(b1 - m1) + (double)ebt1[idx]);
    sW[c] = ew2[idx];
  }
  int row = (blk << 6) + l;
  float fv = f[row];
  const float* dd = dw + (size_t)row*KN;
  float b2v = eb2[br];
  float P[16];
#pragma unroll
  for (int c=0;c<16;c++) P[c] = fmaf(sA[c], fv, sC[c]);
  float mx = -INFINITY, mn = INFINITY;
  double s = 0.0, s2 = 0.0;
  for (int k=0;k<KN;k++) {
    float d = dd[k];
    float t = b2v;
#pragma unroll
    for (int c=0;c<16;c++)
      t = fmaf(sW[c], fmaxf(fmaf(sB[c], d, P[c]), 0.f), t);
    mx = fmaxf(mx, t);
    mn = fminf(mn, t);
    double td = (double)t;
    s += td; s2 += td*td;
  }
  maxo[br*16384 + row] = mx;
  mino[br*16384 + row] = mn;
#pragma unroll
  for (int off=32; off>0; off>>=1) {
    s  += __shfl_down(s, off, 64);
    s2 += __shfl_down(s2, off, 64);
  }
  if (l == 0) {
    part2[(br*256 + blk)*2 + 0] = s;
    part2[(br*256 + blk)*2 + 1] = s2;
  }
}

// ===== K6: redundant BN2 fold + pixel shuffle + sigmoid =====
__global__ __launch_bounds__(256) void out_k(const float* __restrict__ f,
    const float* __restrict__ maxo, const float* __restrict__ mino,
    const double* __restrict__ part2,
    const float* __restrict__ eg2, const float* __restrict__ ebt2,
    float* __restrict__ out) {
  __shared__ float c2c[3][2];
  const int tid = threadIdx.x, blk = blockIdx.x;
  const int l = tid & 63, w = tid >> 6;
  if (w < 3) {
    int br = w;
    double s = 0.0, s2 = 0.0;
#pragma unroll
    for (int i=0;i<4;i++) {
      int bb = l + (i << 6);
      s  += part2[(br*256 + bb)*2 + 0];
      s2 += part2[(br*256 + bb)*2 + 1];
    }
#pragma unroll
    for (int off=32; off>0; off>>=1) {
      s  += __shfl_down(s, off, 64);
      s2 += __shfl_down(s2, off, 64);
    }
    if (l == 0) {
      double mean = s / MTOT;
      double var = s2 / MTOT - mean*mean;
      double r2 = 1.0 / sqrt(var + 1e-5);
      double sc = (double)eg2[br] * r2;
      c2c[br][0] = (float)sc;
      c2c[br][1] = (float)((double)ebt2[br] - sc*mean);
    }
  }
  __syncthreads();
  int tg = (blk << 8) + tid;     // 65536
  int bo = tg >> 14;
  int y = (tg >> 7) & 127, xx = tg & 127;
  int n = ((y>>1)<<6) + (xx>>1);
  int ch = ((y&1)<<1) + (xx&1);
  float v;
  if (ch == 0) {
    v = f[bo*NPIX + n];
  } else {
    int br = ch - 1;
    float sc = c2c[br][0], sh = c2c[br][1];
    float base = (sc >= 0.f) ? maxo[br*16384 + bo*NPIX + n]
                             : mino[br*16384 + bo*NPIX + n];
    v = fmaxf(fmaf(sc, base, sh), 0.f);
  }
  out[tg] = 1.f / (1.f + expf(-v));
}

extern "C" void kernel_launch(void* const* d_in, const int* in_sizes, int n_in,
                              void* d_out, int out_size, void* d_ws, size_t ws_size,
                              hipStream_t stream) {
  (void)in_sizes; (void)n_in; (void)out_size; (void)ws_size;
  const float* x    = (const float*)d_in[0];
  const float* c1w  = (const float*)d_in[1];
  const float* c1b  = (const float*)d_in[2];
  const float* c2w  = (const float*)d_in[3];
  const float* c2b  = (const float*)d_in[4];
  const float* c3w  = (const float*)d_in[5];
  const float* c3b  = (const float*)d_in[6];
  const float* c4w  = (const float*)d_in[7];
  const float* c4b  = (const float*)d_in[8];
  const float* ew1  = (const float*)d_in[9];
  const float* eb1  = (const float*)d_in[10];
  const float* eg1  = (const float*)d_in[11];
  const float* ebt1 = (const float*)d_in[12];
  const float* ew2  = (const float*)d_in[13];
  const float* eb2  = (const float*)d_in[14];
  const float* eg2  = (const float*)d_in[15];
  const float* ebt2 = (const float*)d_in[16];
  float* out = (float*)d_out;
  float* ws  = (float*)d_ws;

  float*  part12 = ws;                       // 2097152 floats (4 x 4 x 32 x 4096)
  float*  fbuf  = ws + 2097152;              // 16384
  float*  dw    = ws + 2113536;              // 327680
  float*  sval  = ws + 2441216;              // 16384
  int*    sidx  = (int*)(ws + 2457600);      // 16384
  float*  maxo  = ws + 2473984;              // 49152
  float*  mino  = ws + 2523136;              // 49152
  double* part1 = (double*)(ws + 2572288);   // 512*5 doubles
  double* part2 = (double*)(ws + 2577408);   // 256*3*2 doubles

  conv12_k<<<dim3(4,64,4), 512, 0, stream>>>(x, c1w, c1b, c2w, c2b, part12);
  conv34_k<<<dim3(4,128), 512, 0, stream>>>(part12, c3w, c3b, c4w, c4b, fbuf);
  sort2_k<<<4, 1024, 0, stream>>>(fbuf, sval, sidx);
  knn4_k<<<512, 512, 0, stream>>>(fbuf, sval, sidx, dw, part1);
  branch_k<<<dim3(256,3), 64, 0, stream>>>(fbuf, dw, part1,
      ew1, eb1, eg1, ebt1, ew2, eb2, maxo, mino, part2);
  out_k<<<256, 256, 0, stream>>>(fbuf, maxo, mino, part2, eg2, ebt2, out);
}

// Round 17
// 104.553 us; speedup vs baseline: 1.1757x; 1.0953x over previous
//
#include <hip/hip_runtime.h>
#include <math.h>

#define NPIX 4096
#define KN 20
#define MTOT 327680.0    // B*N*K

__device__ inline unsigned long long shflx64(unsigned long long v, int m) {
  unsigned lo = (unsigned)v, hi = (unsigned)(v >> 32);
  lo = __shfl_xor(lo, m, 64);
  hi = __shfl_xor(hi, m, 64);
  return (((unsigned long long)hi) << 32) | lo;
}

// ===== K1: conv1 (5x5,1->64,tanh, zero-outside) + conv2 partial, register-tiled =====
// Grid (4,16,4): 16x16 tile, block z handles conv1 couts / conv2 cins z*16..+15.
// conv2: thread = (column-quad of 4 px) x (4 couts); 18 LDS reads + 36 uniform
// s_loads reused 4x per ci; 16 independent acc chains; NO cross-wave reduction.
__global__ __launch_bounds__(512) void conv12_k(const float* __restrict__ x,
    const float* __restrict__ c1w, const float* __restrict__ c1b,
    const float* __restrict__ c2w, const float* __restrict__ c2b,
    float* __restrict__ part12) {
  __shared__ float sx[506];          // 22x22 halo, stride 23
  __shared__ float sc1[5472];        // 16 local ch x (18x18, stride 19)
  const int tid = threadIdx.x;
  const int b = blockIdx.x, tile = blockIdx.y, z = blockIdx.z;
  const int th = (tile >> 2) << 4, tw = (tile & 3) << 4;

  for (int i = tid; i < 484; i += 512) {
    int r = i / 22, c = i - r*22;
    int gr = th - 3 + r, gc = tw - 3 + c;
    sx[r*23 + c] = (gr>=0 && gr<64 && gc>=0 && gc<64) ? x[b*NPIX + (gr<<6) + gc] : 0.f;
  }
  __syncthreads();
  // conv1: 16 local couts on the 18x18 halo (zero outside image)
  for (int idx = tid; idx < 5184; idx += 512) {
    int co = idx / 324, rem = idx - co*324;
    int i = rem / 18, j = rem - i*18;
    int gy = th - 1 + i, gx = tw - 1 + j;
    bool inb = (gy>=0 && gy<64 && gx>=0 && gx<64);
    int cg = (z << 4) + co;
    float acc = c1b[cg];
#pragma unroll
    for (int di=0; di<5; di++)
#pragma unroll
      for (int dj=0; dj<5; dj++)
        acc = fmaf(sx[(i+di)*23 + j+dj], c1w[cg*25 + di*5 + dj], acc);
    sc1[co*342 + i*19 + j] = inb ? tanhf(acc) : 0.f;
  }
  __syncthreads();
  // conv2 partial: wave w -> couts w*4..+3 (uniform); lane -> 4 rows x 1 col
  {
    const int l = tid & 63;
    const int w = __builtin_amdgcn_readfirstlane(tid >> 6);   // 8 waves
    int row0 = (l >> 4) << 2;      // {0,4,8,12}
    int col  = l & 15;             // 0..15
    int co0 = w << 2;
    float acc[16];                 // [p(row)][q(cout)]
#pragma unroll
    for (int p=0;p<4;p++)
#pragma unroll
      for (int q=0;q<4;q++)
        acc[p*4+q] = (z == 0) ? c2b[co0+q] : 0.f;
#pragma unroll 2
    for (int ci = 0; ci < 16; ci++) {
      const float* sp = sc1 + ci*342;
      float vb[6][3];
#pragma unroll
      for (int r=0;r<6;r++)
#pragma unroll
        for (int dj=0;dj<3;dj++)
          vb[r][dj] = sp[(row0+r)*19 + col + dj];
      int cin = (z << 4) + ci;
#pragma unroll
      for (int q=0;q<4;q++) {
        const float* wq = c2w + ((size_t)(co0+q)*64 + cin)*9;
#pragma unroll
        for (int p=0;p<4;p++) {
          float a = acc[p*4+q];
#pragma unroll
          for (int di=0;di<3;di++)
#pragma unroll
            for (int dj=0;dj<3;dj++)
              a = fmaf(vb[p+di][dj], wq[di*3+dj], a);
          acc[p*4+q] = a;
        }
      }
    }
#pragma unroll
    for (int q=0;q<4;q++)
#pragma unroll
      for (int p=0;p<4;p++)
        part12[(((size_t)(z*4 + b)*32 + co0+q) << 12)
               + ((th+row0+p)<<6) + tw + col] = acc[p*4+q];
  }
}

// ===== K2: conv3 (3x3,32->16,tanh, zero-outside) + conv4 (3x3,16->1) =====
// 4x8 tile (grid 4x128). Staging fuses conv2 finalize tanh(p0+p1+p2+p3).
__global__ __launch_bounds__(512) void conv34_k(const float* __restrict__ part12,
    const float* __restrict__ c3w, const float* __restrict__ c3b,
    const float* __restrict__ c4w, const float* __restrict__ c4b,
    float* __restrict__ fbuf) {
  __shared__ float sc2[3328];        // 32 ch x (8 x 12, stride 13)
  __shared__ float sc3[1248];        // 16 ch x (6 x 10 halo, stride 13)
  __shared__ float red[1200];        // 4 grp x 60 px x 5 (4 couts + pad)
  const int tid = threadIdx.x;
  const int b = blockIdx.x, tile = blockIdx.y;
  const int th = (tile >> 3) << 2, tw = (tile & 7) << 3;
  const int px = tid & 127;
  const int cinw = __builtin_amdgcn_readfirstlane(tid >> 7);  // 0..3, uniform

  for (int i = tid; i < 3072; i += 512) {
    int cin = i / 96, rem = i - cin*96;
    int rr = rem / 12, cc = rem - rr*12;
    int gr = th - 2 + rr, gc = tw - 2 + cc;
    float v = 0.f;
    if (gr>=0 && gr<64 && gc>=0 && gc<64) {
      size_t idx = (((size_t)b*32 + cin) << 12) + (gr<<6) + gc;
      v = tanhf(part12[idx] + part12[idx + 524288] +
                part12[idx + 1048576] + part12[idx + 1572864]);
    }
    sc2[cin*104 + rr*13 + cc] = v;
  }
  __syncthreads();
  float acc[16];
  int pi = px / 10, pj = px - pi*10;     // halo 6x10
  if (px < 60) {
#pragma unroll
    for (int o=0;o<16;o++) acc[o] = (cinw == 0) ? c3b[o] : 0.f;
    for (int ci = 0; ci < 8; ci++) {
      int cin = (cinw << 3) + ci;
      const float* sp = sc2 + cin*104;
      float v[9];
#pragma unroll
      for (int di=0;di<3;di++)
#pragma unroll
        for (int dj=0;dj<3;dj++)
          v[di*3+dj] = sp[(pi+di)*13 + pj+dj];
      const float* wc = c3w + cin*9;
#pragma unroll
      for (int o=0;o<16;o++) {
        const float* wo = wc + o*288;
#pragma unroll
        for (int t=0;t<9;t++)
          acc[o] = fmaf(v[t], wo[t], acc[o]);
      }
    }
  }
  int gy = th - 1 + pi, gx = tw - 1 + pj;
  bool inb = (gy>=0 && gy<64 && gx>=0 && gx<64);
  for (int ch = 0; ch < 4; ch++) {
    __syncthreads();
    if (px < 60) {
#pragma unroll
      for (int cc = 0; cc < 4; cc++)
        red[cinw*300 + px*5 + cc] = acc[(ch<<2) + cc];
    }
    __syncthreads();
    if (px < 60) {
      float s = red[0*300 + px*5 + cinw];
#pragma unroll
      for (int g=1; g<4; g++) s += red[g*300 + px*5 + cinw];
      int co = (ch<<2) + cinw;
      sc3[co*78 + pi*13 + pj] = inb ? tanhf(s) : 0.f;
    }
  }
  __syncthreads();
  if (tid < 32) {
    int py = tid >> 3, qx = tid & 7;
    float acc4 = c4b[0];
    for (int cin = 0; cin < 16; cin++) {
#pragma unroll
      for (int di=0;di<3;di++)
#pragma unroll
        for (int dj=0;dj<3;dj++)
          acc4 = fmaf(sc3[cin*78 + (py+di)*13 + qx+dj], c4w[cin*9 + di*3+dj], acc4);
    }
    fbuf[b*NPIX + ((th+py)<<6) + (tw+qx)] = acc4;
  }
}

// ===== K3: per-batch sort: wave bitonic (256-runs) + merge-path =====
__global__ __launch_bounds__(1024) void sort2_k(const float* __restrict__ f,
    float* __restrict__ sval, int* __restrict__ sidx) {
  int b = blockIdx.x;
  int tid = threadIdx.x;
  int l = tid & 63, w = tid >> 6;
  __shared__ unsigned long long Ab[NPIX];
  __shared__ unsigned long long Bb[NPIX];
  const float* fb = f + b*NPIX;
  unsigned long long key[4];
#pragma unroll
  for (int r=0;r<4;r++) {
    unsigned e = (w<<8) + (r<<6) + l;
    float v = fb[e];
    unsigned u = __float_as_uint(v);
    u ^= (u >> 31) ? 0xFFFFFFFFu : 0x80000000u;   // order-preserving flip
    key[r] = (((unsigned long long)u) << 32) | e;
  }
  for (unsigned k = 2; k <= 256; k <<= 1) {
    for (unsigned j = k >> 1; j > 0; j >>= 1) {
      if (j >= 64) {
        unsigned rj = j >> 6;
#pragma unroll
        for (int r=0;r<4;r++) {
          int pr = r ^ (int)rj;
          if (pr > r) {
            unsigned e = (w<<8)+((unsigned)r<<6)+l;
            bool up = ((e & k & 255u) == 0);
            unsigned long long a = key[r], c = key[pr];
            bool sw = up ? (c < a) : (c > a);
            if (sw) { key[r] = c; key[pr] = a; }
          }
        }
      } else {
#pragma unroll
        for (int r=0;r<4;r++) {
          unsigned e = (w<<8)+((unsigned)r<<6)+l;
          unsigned long long a = key[r];
          unsigned long long p = shflx64(a, (int)j);
          bool up = ((e & k & 255u) == 0);
          bool keepmin = ((e & j) == 0) == up;
          key[r] = (keepmin ? (p < a) : (p > a)) ? p : a;
        }
      }
    }
  }
#pragma unroll
  for (int r=0;r<4;r++) Ab[(w<<8)+(r<<6)+l] = key[r];
  __syncthreads();
  unsigned long long* src = Ab;
  unsigned long long* dst = Bb;
  for (int lg = 8; lg <= 11; lg++) {
    const int L = 1 << lg;
    int p0 = tid << 2;
    int ri = p0 >> lg;
    int base = (ri ^ 1) << lg;
    int mbase = ((ri >> 1) << (lg + 1)) + (p0 & (L - 1));
    unsigned long long kk[4];
    int lo[4], hi[4];
#pragma unroll
    for (int r=0;r<4;r++) { kk[r] = src[p0 + r]; lo[r] = 0; hi[r] = L; }
    for (int s = 0; s <= lg; s++) {
#pragma unroll
      for (int r=0;r<4;r++) {
        if (lo[r] < hi[r]) {
          int mid = (lo[r] + hi[r]) >> 1;
          if (src[base + mid] < kk[r]) lo[r] = mid + 1; else hi[r] = mid;
        }
      }
    }
#pragma unroll
    for (int r=0;r<4;r++) dst[mbase + r + lo[r]] = kk[r];
    __syncthreads();
    unsigned long long* t = src; src = dst; dst = t;
  }
#pragma unroll
  for (int r=0;r<4;r++) {
    int p = (tid << 2) + r;
    unsigned long long kk = src[p];
    unsigned u = (unsigned)(kk >> 32);
    u ^= (u >> 31) ? 0x80000000u : 0xFFFFFFFFu;   // un-flip
    sval[b*NPIX + p] = __uint_as_float(u);
    sidx[b*NPIX + p] = (int)(kk & 0xFFFFFFFFu);
  }
}

// ===== K4: KNN (wave/point ILP-4) + BN1 moment partials =====
__global__ __launch_bounds__(512) void knn4_k(const float* __restrict__ f,
    const float* __restrict__ sval, const int* __restrict__ sidx,
    float* __restrict__ dout, double* __restrict__ part1) {
  const int tid = threadIdx.x, blk = blockIdx.x;   // 512 blocks
  const int l = tid & 63, w = tid >> 6;            // 8 waves
  const int bq = blk >> 7;                          // 128 blocks per batch
  const float* svb = sval + (bq << 12);
  const int*   sib = sidx + (bq << 12);
  const float* fB  = f + (bq << 12);
  double a0=0, a1=0, a2=0, a3=0, a4=0;
  unsigned long long kk[4];
  float fnp[4];
  int   sp[4];
#pragma unroll
  for (int p=0;p<4;p++) {
    int s = ((blk & 127) << 5) + (w << 2) + p;
    sp[p] = s;
    float fn = svb[s]; fnp[p] = fn;
    int start = s - 32;
    if (start < 0) start = 0;
    if (start > NPIX - 64) start = NPIX - 64;
    int q = start + l;
    float fm = svb[q];
    int   m  = sib[q];
    float sqn = __fmul_rn(fn, fn);
    float pr  = __fmul_rn(fn, fm);
    float dist = __fsub_rn(__fadd_rn(sqn, __fmul_rn(fm, fm)), __fmul_rn(2.0f, pr));
    unsigned u = __float_as_uint(dist);
    u ^= (u >> 31) ? 0xFFFFFFFFu : 0x80000000u;
    kk[p] = (((unsigned long long)u) << 32) | (unsigned)m;
  }
#pragma unroll
  for (int k = 2; k <= 64; k <<= 1)
#pragma unroll
    for (int j = k >> 1; j > 0; j >>= 1) {
#pragma unroll
      for (int p=0;p<4;p++) {
        unsigned long long pp = shflx64(kk[p], j);
        bool up = ((l & k) == 0);
        bool keepmin = ((l & j) == 0) == up;
        kk[p] = (keepmin ? (pp < kk[p]) : (pp > kk[p])) ? pp : kk[p];
      }
    }
#pragma unroll
  for (int p=0;p<4;p++) {
    int mr = (int)(kk[p] & 0xFFFFFFFFu);
    float fn = fnp[p];
    float d = __fsub_rn(fB[mr], fn);       // knn - x1, rank l
    int n = sib[sp[p]];
    if (l >= 1 && l <= 20)
      dout[(size_t)((bq<<12) + n)*KN + (l-1)] = d;
    float dm = (l >= 1 && l <= 20) ? d : 0.f;
    a2 += (double)dm;
    a3 += (double)dm * (double)dm;
    a4 += (double)fn * (double)dm;
    if (l == 0) { a0 += (double)fn; a1 += (double)fn * (double)fn; }
  }
  double v[5] = {a0, a1, a2, a3, a4};
#pragma unroll
  for (int qi=0; qi<5; qi++)
    for (int off=32; off>0; off>>=1) v[qi] += __shfl_down(v[qi], off, 64);
  __shared__ double sred[8][5];
  if (l == 0)
#pragma unroll
    for (int qi=0; qi<5; qi++) sred[w][qi] = v[qi];
  __syncthreads();
  if (tid == 0) {
#pragma unroll
    for (int qi=0; qi<5; qi++) {
      double s = 0.0;
#pragma unroll
      for (int ww=0; ww<8; ww++) s += sred[ww][qi];
      part1[blk*5 + qi] = s;
    }
  }
}

// ===== K5: redundant BN1 fold + per-branch o_pre max/min + BN2 partials =====
__global__ __launch_bounds__(64) void branch_k(const float* __restrict__ f,
    const float* __restrict__ dw, const double* __restrict__ part1,
    const float* __restrict__ ew1, const float* __restrict__ eb1,
    const float* __restrict__ eg1, const float* __restrict__ ebt1,
    const float* __restrict__ ew2, const float* __restrict__ eb2,
    float* __restrict__ maxo, float* __restrict__ mino,
    double* __restrict__ part2) {
  const int l = threadIdx.x;
  const int blk = blockIdx.x, br = blockIdx.y;
  double a[5] = {0,0,0,0,0};
  for (int b2 = l; b2 < 512; b2 += 64)
#pragma unroll
    for (int q=0;q<5;q++) a[q] += part1[b2*5+q];
#pragma unroll
  for (int q=0;q<5;q++)
    for (int off=32; off>0; off>>=1) a[q] += __shfl_down(a[q], off, 64);
#pragma unroll
  for (int q=0;q<5;q++) a[q] = __shfl(a[q], 0, 64);
  double Ef = a[0]/16384.0, Eff = a[1]/16384.0;
  double Ed = a[2]/MTOT, Edd = a[3]/MTOT, Efd = a[4]/MTOT;
  double Vf = Eff - Ef*Ef, Vd = Edd - Ed*Ed, Cfd = Efd - Ef*Ed;
  float sA[16], sB[16], sC[16], sW[16];
#pragma unroll
  for (int c=0;c<16;c++) {
    int idx = br*16 + c;
    double w0 = (double)ew1[idx*2+0], w1 = (double)ew1[idx*2+1];
    double b1 = (double)eb1[idx];
    double m1 = w0*Ef + w1*Ed + b1;
    double v1 = w0*w0*Vf + 2.0*w0*w1*Cfd + w1*w1*Vd;
    double r1 = 1.0 / sqrt(v1 + 1e-5);
    double g = (double)eg1[idx];
    sA[c] = (float)(g*r1*w0);
    sB[c] = (float)(g*r1*w1);
    sC[c] = (float)(g*r1*(b1 - m1) + (double)ebt1[idx]);
    sW[c] = ew2[idx];
  }
  int row = (blk << 6) + l;
  float fv = f[row];
  const float* dd = dw + (size_t)row*KN;
  float b2v = eb2[br];
  float P[16];
#pragma unroll
  for (int c=0;c<16;c++) P[c] = fmaf(sA[c], fv, sC[c]);
  float mx = -INFINITY, mn = INFINITY;
  double s = 0.0, s2 = 0.0;
  for (int k=0;k<KN;k++) {
    float d = dd[k];
    float t = b2v;
#pragma unroll
    for (int c=0;c<16;c++)
      t = fmaf(sW[c], fmaxf(fmaf(sB[c], d, P[c]), 0.f), t);
    mx = fmaxf(mx, t);
    mn = fminf(mn, t);
    double td = (double)t;
    s += td; s2 += td*td;
  }
  maxo[br*16384 + row] = mx;
  mino[br*16384 + row] = mn;
#pragma unroll
  for (int off=32; off>0; off>>=1) {
    s  += __shfl_down(s, off, 64);
    s2 += __shfl_down(s2, off, 64);
  }
  if (l == 0) {
    part2[(br*256 + blk)*2 + 0] = s;
    part2[(br*256 + blk)*2 + 1] = s2;
  }
}

// ===== K6: redundant BN2 fold + pixel shuffle + sigmoid =====
__global__ __launch_bounds__(256) void out_k(const float* __restrict__ f,
    const float* __restrict__ maxo, const float* __restrict__ mino,
    const double* __restrict__ part2,
    const float* __restrict__ eg2, const float* __restrict__ ebt2,
    float* __restrict__ out) {
  __shared__ float c2c[3][2];
  const int tid = threadIdx.x, blk = blockIdx.x;
  const int l = tid & 63, w = tid >> 6;
  if (w < 3) {
    int br = w;
    double s = 0.0, s2 = 0.0;
#pragma unroll
    for (int i=0;i<4;i++) {
      int bb = l + (i << 6);
      s  += part2[(br*256 + bb)*2 + 0];
      s2 += part2[(br*256 + bb)*2 + 1];
    }
#pragma unroll
    for (int off=32; off>0; off>>=1) {
      s  += __shfl_down(s, off, 64);
      s2 += __shfl_down(s2, off, 64);
    }
    if (l == 0) {
      double mean = s / MTOT;
      double var = s2 / MTOT - mean*mean;
      double r2 = 1.0 / sqrt(var + 1e-5);
      double sc = (double)eg2[br] * r2;
      c2c[br][0] = (float)sc;
      c2c[br][1] = (float)((double)ebt2[br] - sc*mean);
    }
  }
  __syncthreads();
  int tg = (blk << 8) + tid;     // 65536
  int bo = tg >> 14;
  int y = (tg >> 7) & 127, xx = tg & 127;
  int n = ((y>>1)<<6) + (xx>>1);
  int ch = ((y&1)<<1) + (xx&1);
  float v;
  if (ch == 0) {
    v = f[bo*NPIX + n];
  } else {
    int br = ch - 1;
    float sc = c2c[br][0], sh = c2c[br][1];
    float base = (sc >= 0.f) ? maxo[br*16384 + bo*NPIX + n]
                             : mino[br*16384 + bo*NPIX + n];
    v = fmaxf(fmaf(sc, base, sh), 0.f);
  }
  out[tg] = 1.f / (1.f + expf(-v));
}

extern "C" void kernel_launch(void* const* d_in, const int* in_sizes, int n_in,
                              void* d_out, int out_size, void* d_ws, size_t ws_size,
                              hipStream_t stream) {
  (void)in_sizes; (void)n_in; (void)out_size; (void)ws_size;
  const float* x    = (const float*)d_in[0];
  const float* c1w  = (const float*)d_in[1];
  const float* c1b  = (const float*)d_in[2];
  const float* c2w  = (const float*)d_in[3];
  const float* c2b  = (const float*)d_in[4];
  const float* c3w  = (const float*)d_in[5];
  const float* c3b  = (const float*)d_in[6];
  const float* c4w  = (const float*)d_in[7];
  const float* c4b  = (const float*)d_in[8];
  const float* ew1  = (const float*)d_in[9];
  const float* eb1  = (const float*)d_in[10];
  const float* eg1  = (const float*)d_in[11];
  const float* ebt1 = (const float*)d_in[12];
  const float* ew2  = (const float*)d_in[13];
  const float* eb2  = (const float*)d_in[14];
  const float* eg2  = (const float*)d_in[15];
  const float* ebt2 = (const float*)d_in[16];
  float* out = (float*)d_out;
  float* ws  = (float*)d_ws;

  float*  part12 = ws;                       // 2097152 floats (4 x 4 x 32 x 4096)
  float*  fbuf  = ws + 2097152;              // 16384
  float*  dw    = ws + 2113536;              // 327680
  float*  sval  = ws + 2441216;              // 16384
  int*    sidx  = (int*)(ws + 2457600);      // 16384
  float*  maxo  = ws + 2473984;              // 49152
  float*  mino  = ws + 2523136;              // 49152
  double* part1 = (double*)(ws + 2572288);   // 512*5 doubles
  double* part2 = (double*)(ws + 2577408);   // 256*3*2 doubles

  conv12_k<<<dim3(4,16,4), 512, 0, stream>>>(x, c1w, c1b, c2w, c2b, part12);
  conv34_k<<<dim3(4,128), 512, 0, stream>>>(part12, c3w, c3b, c4w, c4b, fbuf);
  sort2_k<<<4, 1024, 0, stream>>>(fbuf, sval, sidx);
  knn4_k<<<512, 512, 0, stream>>>(fbuf, sval, sidx, dw, part1);
  branch_k<<<dim3(256,3), 64, 0, stream>>>(fbuf, dw, part1,
      ew1, eb1, eg1, ebt1, ew2, eb2, maxo, mino, part2);
  out_k<<<256, 256, 0, stream>>>(fbuf, maxo, mino, part2, eg2, ebt2, out);
}

// Round 18
// 104.293 us; speedup vs baseline: 1.1786x; 1.0025x over previous
//
#include <hip/hip_runtime.h>
#include <math.h>

#define NPIX 4096
#define KN 20
#define MTOT 327680.0    // B*N*K

__device__ inline unsigned long long shflx64(unsigned long long v, int m) {
  unsigned lo = (unsigned)v, hi = (unsigned)(v >> 32);
  lo = __shfl_xor(lo, m, 64);
  hi = __shfl_xor(hi, m, 64);
  return (((unsigned long long)hi) << 32) | lo;
}

// ===== K1: conv1 (5x5,1->64,tanh, zero-outside) + conv2 partial, register-tiled =====
// Grid (4,16,4): 16x16 tile, block z handles conv1 couts / conv2 cins z*16..+15.
__global__ __launch_bounds__(512) void conv12_k(const float* __restrict__ x,
    const float* __restrict__ c1w, const float* __restrict__ c1b,
    const float* __restrict__ c2w, const float* __restrict__ c2b,
    float* __restrict__ part12) {
  __shared__ float sx[506];          // 22x22 halo, stride 23
  __shared__ float sc1[5472];        // 16 local ch x (18x18, stride 19)
  const int tid = threadIdx.x;
  const int b = blockIdx.x, tile = blockIdx.y, z = blockIdx.z;
  const int th = (tile >> 2) << 4, tw = (tile & 3) << 4;

  for (int i = tid; i < 484; i += 512) {
    int r = i / 22, c = i - r*22;
    int gr = th - 3 + r, gc = tw - 3 + c;
    sx[r*23 + c] = (gr>=0 && gr<64 && gc>=0 && gc<64) ? x[b*NPIX + (gr<<6) + gc] : 0.f;
  }
  __syncthreads();
  // conv1: 16 local couts on the 18x18 halo (zero outside image)
  for (int idx = tid; idx < 5184; idx += 512) {
    int co = idx / 324, rem = idx - co*324;
    int i = rem / 18, j = rem - i*18;
    int gy = th - 1 + i, gx = tw - 1 + j;
    bool inb = (gy>=0 && gy<64 && gx>=0 && gx<64);
    int cg = (z << 4) + co;
    float acc = c1b[cg];
#pragma unroll
    for (int di=0; di<5; di++)
#pragma unroll
      for (int dj=0; dj<5; dj++)
        acc = fmaf(sx[(i+di)*23 + j+dj], c1w[cg*25 + di*5 + dj], acc);
    sc1[co*342 + i*19 + j] = inb ? tanhf(acc) : 0.f;
  }
  __syncthreads();
  // conv2 partial: wave w -> couts w*4..+3 (uniform); lane -> 4 rows x 1 col
  {
    const int l = tid & 63;
    const int w = __builtin_amdgcn_readfirstlane(tid >> 6);   // 8 waves
    int row0 = (l >> 4) << 2;      // {0,4,8,12}
    int col  = l & 15;             // 0..15
    int co0 = w << 2;
    float acc[16];                 // [p(row)][q(cout)]
#pragma unroll
    for (int p=0;p<4;p++)
#pragma unroll
      for (int q=0;q<4;q++)
        acc[p*4+q] = (z == 0) ? c2b[co0+q] : 0.f;
#pragma unroll 2
    for (int ci = 0; ci < 16; ci++) {
      const float* sp = sc1 + ci*342;
      float vb[6][3];
#pragma unroll
      for (int r=0;r<6;r++)
#pragma unroll
        for (int dj=0;dj<3;dj++)
          vb[r][dj] = sp[(row0+r)*19 + col + dj];
      int cin = (z << 4) + ci;
#pragma unroll
      for (int q=0;q<4;q++) {
        const float* wq = c2w + ((size_t)(co0+q)*64 + cin)*9;
#pragma unroll
        for (int p=0;p<4;p++) {
          float a = acc[p*4+q];
#pragma unroll
          for (int di=0;di<3;di++)
#pragma unroll
            for (int dj=0;dj<3;dj++)
              a = fmaf(vb[p+di][dj], wq[di*3+dj], a);
          acc[p*4+q] = a;
        }
      }
    }
#pragma unroll
    for (int q=0;q<4;q++)
#pragma unroll
      for (int p=0;p<4;p++)
        part12[(((size_t)(z*4 + b)*32 + co0+q) << 12)
               + ((th+row0+p)<<6) + tw + col] = acc[p*4+q];
  }
}

// ===== K2: conv3 (3x3,32->16,tanh, zero-outside) + conv4 (3x3,16->1), register-tiled =====
// 8x8 tile (grid 4x64 = 256 blocks). Thread = halo-px (tid&127, <100) x 4 couts
// (tid>>7, wave-uniform). Full 32-cin range per thread: no reduction, 2 barriers.
__global__ __launch_bounds__(512) void conv34_k(const float* __restrict__ part12,
    const float* __restrict__ c3w, const float* __restrict__ c3b,
    const float* __restrict__ c4w, const float* __restrict__ c4b,
    float* __restrict__ fbuf) {
  __shared__ float sc2[4992];        // 32 ch x (12x12 halo, stride 13)
  __shared__ float sc3[2080];        // 16 ch x (10x10 halo, stride 13)
  const int tid = threadIdx.x;
  const int b = blockIdx.x, tile = blockIdx.y;
  const int th = (tile >> 3) << 3, tw = (tile & 7) << 3;
  const int px = tid & 127;
  const int coutg = __builtin_amdgcn_readfirstlane(tid >> 7);  // 0..3, uniform

  // stage conv2 12x12 halo, fusing finalize: tanh(p0+p1+p2+p3), zero outside
  for (int i = tid; i < 4608; i += 512) {
    int cin = i / 144, rem = i - cin*144;
    int rr = rem / 12, cc = rem - rr*12;
    int gr = th - 2 + rr, gc = tw - 2 + cc;
    float v = 0.f;
    if (gr>=0 && gr<64 && gc>=0 && gc<64) {
      size_t idx = (((size_t)b*32 + cin) << 12) + (gr<<6) + gc;
      v = tanhf(part12[idx] + part12[idx + 524288] +
                part12[idx + 1048576] + part12[idx + 1572864]);
    }
    sc2[cin*156 + rr*13 + cc] = v;
  }
  __syncthreads();
  // conv3 on 10x10 halo; thread = px x 4 couts, sequential cin 0..31
  if (px < 100) {
    int pi = px / 10, pj = px - pi*10;
    int co0 = coutg << 2;
    float a0 = c3b[co0+0], a1 = c3b[co0+1], a2 = c3b[co0+2], a3 = c3b[co0+3];
    for (int cin = 0; cin < 32; cin++) {
      const float* sp = sc2 + cin*156;
      float v[9];
#pragma unroll
      for (int di=0;di<3;di++)
#pragma unroll
        for (int dj=0;dj<3;dj++)
          v[di*3+dj] = sp[(pi+di)*13 + pj+dj];
      const float* wc = c3w + cin*9;
      const float* w0p = wc + (size_t)(co0+0)*288;
      const float* w1p = wc + (size_t)(co0+1)*288;
      const float* w2p = wc + (size_t)(co0+2)*288;
      const float* w3p = wc + (size_t)(co0+3)*288;
#pragma unroll
      for (int t=0;t<9;t++) {
        a0 = fmaf(v[t], w0p[t], a0);
        a1 = fmaf(v[t], w1p[t], a1);
        a2 = fmaf(v[t], w2p[t], a2);
        a3 = fmaf(v[t], w3p[t], a3);
      }
    }
    int gy = th - 1 + pi, gx = tw - 1 + pj;
    bool inb = (gy>=0 && gy<64 && gx>=0 && gx<64);
    sc3[(co0+0)*130 + pi*13 + pj] = inb ? tanhf(a0) : 0.f;
    sc3[(co0+1)*130 + pi*13 + pj] = inb ? tanhf(a1) : 0.f;
    sc3[(co0+2)*130 + pi*13 + pj] = inb ? tanhf(a2) : 0.f;
    sc3[(co0+3)*130 + pi*13 + pj] = inb ? tanhf(a3) : 0.f;
  }
  __syncthreads();
  if (tid < 64) {
    int py = tid >> 3, qx = tid & 7;
    float acc4 = c4b[0];
    for (int cin = 0; cin < 16; cin++) {
#pragma unroll
      for (int di=0;di<3;di++)
#pragma unroll
        for (int dj=0;dj<3;dj++)
          acc4 = fmaf(sc3[cin*130 + (py+di)*13 + qx+dj], c4w[cin*9 + di*3+dj], acc4);
    }
    fbuf[b*NPIX + ((th+py)<<6) + (tw+qx)] = acc4;
  }
}

// ===== K3: per-batch sort: wave bitonic (256-runs) + merge-path =====
__global__ __launch_bounds__(1024) void sort2_k(const float* __restrict__ f,
    float* __restrict__ sval, int* __restrict__ sidx) {
  int b = blockIdx.x;
  int tid = threadIdx.x;
  int l = tid & 63, w = tid >> 6;
  __shared__ unsigned long long Ab[NPIX];
  __shared__ unsigned long long Bb[NPIX];
  const float* fb = f + b*NPIX;
  unsigned long long key[4];
#pragma unroll
  for (int r=0;r<4;r++) {
    unsigned e = (w<<8) + (r<<6) + l;
    float v = fb[e];
    unsigned u = __float_as_uint(v);
    u ^= (u >> 31) ? 0xFFFFFFFFu : 0x80000000u;   // order-preserving flip
    key[r] = (((unsigned long long)u) << 32) | e;
  }
  for (unsigned k = 2; k <= 256; k <<= 1) {
    for (unsigned j = k >> 1; j > 0; j >>= 1) {
      if (j >= 64) {
        unsigned rj = j >> 6;
#pragma unroll
        for (int r=0;r<4;r++) {
          int pr = r ^ (int)rj;
          if (pr > r) {
            unsigned e = (w<<8)+((unsigned)r<<6)+l;
            bool up = ((e & k & 255u) == 0);
            unsigned long long a = key[r], c = key[pr];
            bool sw = up ? (c < a) : (c > a);
            if (sw) { key[r] = c; key[pr] = a; }
          }
        }
      } else {
#pragma unroll
        for (int r=0;r<4;r++) {
          unsigned e = (w<<8)+((unsigned)r<<6)+l;
          unsigned long long a = key[r];
          unsigned long long p = shflx64(a, (int)j);
          bool up = ((e & k & 255u) == 0);
          bool keepmin = ((e & j) == 0) == up;
          key[r] = (keepmin ? (p < a) : (p > a)) ? p : a;
        }
      }
    }
  }
#pragma unroll
  for (int r=0;r<4;r++) Ab[(w<<8)+(r<<6)+l] = key[r];
  __syncthreads();
  unsigned long long* src = Ab;
  unsigned long long* dst = Bb;
  for (int lg = 8; lg <= 11; lg++) {
    const int L = 1 << lg;
    int p0 = tid << 2;
    int ri = p0 >> lg;
    int base = (ri ^ 1) << lg;
    int mbase = ((ri >> 1) << (lg + 1)) + (p0 & (L - 1));
    unsigned long long kk[4];
    int lo[4], hi[4];
#pragma unroll
    for (int r=0;r<4;r++) { kk[r] = src[p0 + r]; lo[r] = 0; hi[r] = L; }
    for (int s = 0; s <= lg; s++) {
#pragma unroll
      for (int r=0;r<4;r++) {
        if (lo[r] < hi[r]) {
          int mid = (lo[r] + hi[r]) >> 1;
          if (src[base + mid] < kk[r]) lo[r] = mid + 1; else hi[r] = mid;
        }
      }
    }
#pragma unroll
    for (int r=0;r<4;r++) dst[mbase + r + lo[r]] = kk[r];
    __syncthreads();
    unsigned long long* t = src; src = dst; dst = t;
  }
#pragma unroll
  for (int r=0;r<4;r++) {
    int p = (tid << 2) + r;
    unsigned long long kk = src[p];
    unsigned u = (unsigned)(kk >> 32);
    u ^= (u >> 31) ? 0x80000000u : 0xFFFFFFFFu;   // un-flip
    sval[b*NPIX + p] = __uint_as_float(u);
    sidx[b*NPIX + p] = (int)(kk & 0xFFFFFFFFu);
  }
}

// ===== K4: KNN (wave/point ILP-4) + BN1 moment partials =====
__global__ __launch_bounds__(512) void knn4_k(const float* __restrict__ f,
    const float* __restrict__ sval, const int* __restrict__ sidx,
    float* __restrict__ dout, double* __restrict__ part1) {
  const int tid = threadIdx.x, blk = blockIdx.x;   // 512 blocks
  const int l = tid & 63, w = tid >> 6;            // 8 waves
  const int bq = blk >> 7;                          // 128 blocks per batch
  const float* svb = sval + (bq << 12);
  const int*   sib = sidx + (bq << 12);
  const float* fB  = f + (bq << 12);
  double a0=0, a1=0, a2=0, a3=0, a4=0;
  unsigned long long kk[4];
  float fnp[4];
  int   sp[4];
#pragma unroll
  for (int p=0;p<4;p++) {
    int s = ((blk & 127) << 5) + (w << 2) + p;
    sp[p] = s;
    float fn = svb[s]; fnp[p] = fn;
    int start = s - 32;
    if (start < 0) start = 0;
    if (start > NPIX - 64) start = NPIX - 64;
    int q = start + l;
    float fm = svb[q];
    int   m  = sib[q];
    float sqn = __fmul_rn(fn, fn);
    float pr  = __fmul_rn(fn, fm);
    float dist = __fsub_rn(__fadd_rn(sqn, __fmul_rn(fm, fm)), __fmul_rn(2.0f, pr));
    unsigned u = __float_as_uint(dist);
    u ^= (u >> 31) ? 0xFFFFFFFFu : 0x80000000u;
    kk[p] = (((unsigned long long)u) << 32) | (unsigned)m;
  }
#pragma unroll
  for (int k = 2; k <= 64; k <<= 1)
#pragma unroll
    for (int j = k >> 1; j > 0; j >>= 1) {
#pragma unroll
      for (int p=0;p<4;p++) {
        unsigned long long pp = shflx64(kk[p], j);
        bool up = ((l & k) == 0);
        bool keepmin = ((l & j) == 0) == up;
        kk[p] = (keepmin ? (pp < kk[p]) : (pp > kk[p])) ? pp : kk[p];
      }
    }
#pragma unroll
  for (int p=0;p<4;p++) {
    int mr = (int)(kk[p] & 0xFFFFFFFFu);
    float fn = fnp[p];
    float d = __fsub_rn(fB[mr], fn);       // knn - x1, rank l
    int n = sib[sp[p]];
    if (l >= 1 && l <= 20)
      dout[(size_t)((bq<<12) + n)*KN + (l-1)] = d;
    float dm = (l >= 1 && l <= 20) ? d : 0.f;
    a2 += (double)dm;
    a3 += (double)dm * (double)dm;
    a4 += (double)fn * (double)dm;
    if (l == 0) { a0 += (double)fn; a1 += (double)fn * (double)fn; }
  }
  double v[5] = {a0, a1, a2, a3, a4};
#pragma unroll
  for (int qi=0; qi<5; qi++)
    for (int off=32; off>0; off>>=1) v[qi] += __shfl_down(v[qi], off, 64);
  __shared__ double sred[8][5];
  if (l == 0)
#pragma unroll
    for (int qi=0; qi<5; qi++) sred[w][qi] = v[qi];
  __syncthreads();
  if (tid == 0) {
#pragma unroll
    for (int qi=0; qi<5; qi++) {
      double s = 0.0;
#pragma unroll
      for (int ww=0; ww<8; ww++) s += sred[ww][qi];
      part1[blk*5 + qi] = s;
    }
  }
}

// ===== K5: redundant BN1 fold + per-branch o_pre max/min + BN2 partials =====
__global__ __launch_bounds__(64) void branch_k(const float* __restrict__ f,
    const float* __restrict__ dw, const double* __restrict__ part1,
    const float* __restrict__ ew1, const float* __restrict__ eb1,
    const float* __restrict__ eg1, const float* __restrict__ ebt1,
    const float* __restrict__ ew2, const float* __restrict__ eb2,
    float* __restrict__ maxo, float* __restrict__ mino,
    double* __restrict__ part2) {
  const int l = threadIdx.x;
  const int blk = blockIdx.x, br = blockIdx.y;
  double a[5] = {0,0,0,0,0};
  for (int b2 = l; b2 < 512; b2 += 64)
#pragma unroll
    for (int q=0;q<5;q++) a[q] += part1[b2*5+q];
#pragma unroll
  for (int q=0;q<5;q++)
    for (int off=32; off>0; off>>=1) a[q] += __shfl_down(a[q], off, 64);
#pragma unroll
  for (int q=0;q<5;q++) a[q] = __shfl(a[q], 0, 64);
  double Ef = a[0]/16384.0, Eff = a[1]/16384.0;
  double Ed = a[2]/MTOT, Edd = a[3]/MTOT, Efd = a[4]/MTOT;
  double Vf = Eff - Ef*Ef, Vd = Edd - Ed*Ed, Cfd = Efd - Ef*Ed;
  float sA[16], sB[16], sC[16], sW[16];
#pragma unroll
  for (int c=0;c<16;c++) {
    int idx = br*16 + c;
    double w0 = (double)ew1[idx*2+0], w1 = (double)ew1[idx*2+1];
    double b1 = (double)eb1[idx];
    double m1 = w0*Ef + w1*Ed + b1;
    double v1 = w0*w0*Vf + 2.0*w0*w1*Cfd + w1*w1*Vd;
    double r1 = 1.0 / sqrt(v1 + 1e-5);
    double g = (double)eg1[idx];
    sA[c] = (float)(g*r1*w0);
    sB[c] = (float)(g*r1*w1);
    sC[c] = (float)(g*r1*(b1 - m1) + (double)ebt1[idx]);
    sW[c] = ew2[idx];
  }
  int row = (blk << 6) + l;
  float fv = f[row];
  const float* dd = dw + (size_t)row*KN;
  float b2v = eb2[br];
  float P[16];
#pragma unroll
  for (int c=0;c<16;c++) P[c] = fmaf(sA[c], fv, sC[c]);
  float mx = -INFINITY, mn = INFINITY;
  double s = 0.0, s2 = 0.0;
  for (int k=0;k<KN;k++) {
    float d = dd[k];
    float t = b2v;
#pragma unroll
    for (int c=0;c<16;c++)
      t = fmaf(sW[c], fmaxf(fmaf(sB[c], d, P[c]), 0.f), t);
    mx = fmaxf(mx, t);
    mn = fminf(mn, t);
    double td = (double)t;
    s += td; s2 += td*td;
  }
  maxo[br*16384 + row] = mx;
  mino[br*16384 + row] = mn;
#pragma unroll
  for (int off=32; off>0; off>>=1) {
    s  += __shfl_down(s, off, 64);
    s2 += __shfl_down(s2, off, 64);
  }
  if (l == 0) {
    part2[(br*256 + blk)*2 + 0] = s;
    part2[(br*256 + blk)*2 + 1] = s2;
  }
}

// ===== K6: redundant BN2 fold + pixel shuffle + sigmoid =====
__global__ __launch_bounds__(256) void out_k(const float* __restrict__ f,
    const float* __restrict__ maxo, const float* __restrict__ mino,
    const double* __restrict__ part2,
    const float* __restrict__ eg2, const float* __restrict__ ebt2,
    float* __restrict__ out) {
  __shared__ float c2c[3][2];
  const int tid = threadIdx.x, blk = blockIdx.x;
  const int l = tid & 63, w = tid >> 6;
  if (w < 3) {
    int br = w;
    double s = 0.0, s2 = 0.0;
#pragma unroll
    for (int i=0;i<4;i++) {
      int bb = l + (i << 6);
      s  += part2[(br*256 + bb)*2 + 0];
      s2 += part2[(br*256 + bb)*2 + 1];
    }
#pragma unroll
    for (int off=32; off>0; off>>=1) {
      s  += __shfl_down(s, off, 64);
      s2 += __shfl_down(s2, off, 64);
    }
    if (l == 0) {
      double mean = s / MTOT;
      double var = s2 / MTOT - mean*mean;
      double r2 = 1.0 / sqrt(var + 1e-5);
      double sc = (double)eg2[br] * r2;
      c2c[br][0] = (float)sc;
      c2c[br][1] = (float)((double)ebt2[br] - sc*mean);
    }
  }
  __syncthreads();
  int tg = (blk << 8) + tid;     // 65536
  int bo = tg >> 14;
  int y = (tg >> 7) & 127, xx = tg & 127;
  int n = ((y>>1)<<6) + (xx>>1);
  int ch = ((y&1)<<1) + (xx&1);
  float v;
  if (ch == 0) {
    v = f[bo*NPIX + n];
  } else {
    int br = ch - 1;
    float sc = c2c[br][0], sh = c2c[br][1];
    float base = (sc >= 0.f) ? maxo[br*16384 + bo*NPIX + n]
                             : mino[br*16384 + bo*NPIX + n];
    v = fmaxf(fmaf(sc, base, sh), 0.f);
  }
  out[tg] = 1.f / (1.f + expf(-v));
}

extern "C" void kernel_launch(void* const* d_in, const int* in_sizes, int n_in,
                              void* d_out, int out_size, void* d_ws, size_t ws_size,
                              hipStream_t stream) {
  (void)in_sizes; (void)n_in; (void)out_size; (void)ws_size;
  const float* x    = (const float*)d_in[0];
  const float* c1w  = (const float*)d_in[1];
  const float* c1b  = (const float*)d_in[2];
  const float* c2w  = (const float*)d_in[3];
  const float* c2b  = (const float*)d_in[4];
  const float* c3w  = (const float*)d_in[5];
  const float* c3b  = (const float*)d_in[6];
  const float* c4w  = (const float*)d_in[7];
  const float* c4b  = (const float*)d_in[8];
  const float* ew1  = (const float*)d_in[9];
  const float* eb1  = (const float*)d_in[10];
  const float* eg1  = (const float*)d_in[11];
  const float* ebt1 = (const float*)d_in[12];
  const float* ew2  = (const float*)d_in[13];
  const float* eb2  = (const float*)d_in[14];
  const float* eg2  = (const float*)d_in[15];
  const float* ebt2 = (const float*)d_in[16];
  float* out = (float*)d_out;
  float* ws  = (float*)d_ws;

  float*  part12 = ws;                       // 2097152 floats (4 x 4 x 32 x 4096)
  float*  fbuf  = ws + 2097152;              // 16384
  float*  dw    = ws + 2113536;              // 327680
  float*  sval  = ws + 2441216;              // 16384
  int*    sidx  = (int*)(ws + 2457600);      // 16384
  float*  maxo  = ws + 2473984;              // 49152
  float*  mino  = ws + 2523136;              // 49152
  double* part1 = (double*)(ws + 2572288);   // 512*5 doubles
  double* part2 = (double*)(ws + 2577408);   // 256*3*2 doubles

  conv12_k<<<dim3(4,16,4), 512, 0, stream>>>(x, c1w, c1b, c2w, c2b, part12);
  conv34_k<<<dim3(4,64), 512, 0, stream>>>(part12, c3w, c3b, c4w, c4b, fbuf);
  sort2_k<<<4, 1024, 0, stream>>>(fbuf, sval, sidx);
  knn4_k<<<512, 512, 0, stream>>>(fbuf, sval, sidx, dw, part1);
  branch_k<<<dim3(256,3), 64, 0, stream>>>(fbuf, dw, part1,
      ew1, eb1, eg1, ebt1, ew2, eb2, maxo, mino, part2);
  out_k<<<256, 256, 0, stream>>>(fbuf, maxo, mino, part2, eg2, ebt2, out);
}